// Round 5
// baseline (382.404 us; speedup 1.0000x reference)
//
#include <hip/hip_runtime.h>
#include <hip/hip_bf16.h>
#include <math.h>

// SeaLiceGLKAN — fp32 in/out. R19: hardened R18. Larval gather split out of
// hop0 (per-kernel gather working set 2.56MB -> fits 4MiB XCD L2), 2x-unrolled
// gather loops. dsort restored to its own kernel (exact R17 code); no
// min-waves launch_bounds pins. Per-edge accumulation order preserved exactly.

constexpr int cB = 2, cT = 4, cN = 10000, cF = 16, cH = 64, cE = 160000, cK = 3;
constexpr int cBN = cB * cN;    // 20000
constexpr int cBNH = cBN * cH;  // 1,280,000
constexpr int NBLK = (cBN + 63) / 64;  // 313 nodegroups of 64

typedef const float* fp;
typedef short short8 __attribute__((ext_vector_type(8)));
typedef float f32x4 __attribute__((ext_vector_type(4)));
typedef unsigned short u16;

constexpr float cEXPM2 = 0.13533528323661270f;  // exp(-2)

__device__ __forceinline__ float wsum(float v) {
#pragma unroll
  for (int o = 1; o < 64; o <<= 1) v += __shfl_xor(v, o, 64);
  return v;
}
__device__ __forceinline__ u16 f2b(float f) {  // fp32 -> bf16 bits (RNE)
  unsigned u = __float_as_uint(f);
  u += 0x7FFFu + ((u >> 16) & 1u);
  return (u16)(u >> 16);
}
__device__ __forceinline__ float b2f(u16 b) { return __uint_as_float(((unsigned)b) << 16); }
__device__ __forceinline__ float ftanh(float x) {
  float e = __expf(2.f * x);
  return (e - 1.f) / (e + 1.f);
}

// ---------------- CSR build ----------------
__global__ void k_count(const int* dst, int* counts) {
  int e = blockIdx.x * 256 + threadIdx.x;
  if (e < cE) atomicAdd(&counts[dst[e]], 1);
}

__global__ void k_scan(const int* counts, int* row_ptr, int* cursor) {
  __shared__ int part[1024];
  int t = threadIdx.x;
  const int CH = (cN + 1023) / 1024;  // 10
  int s = 0;
  for (int i = 0; i < CH; i++) {
    int idx = t * CH + i;
    if (idx < cN) s += counts[idx];
  }
  part[t] = s;
  __syncthreads();
  for (int off = 1; off < 1024; off <<= 1) {
    int v = (t >= off) ? part[t - off] : 0;
    __syncthreads();
    part[t] += v;
    __syncthreads();
  }
  int excl = (t == 0) ? 0 : part[t - 1];
  for (int i = 0; i < CH; i++) {
    int idx = t * CH + i;
    if (idx < cN) {
      row_ptr[idx] = excl;
      cursor[idx] = excl;
      excl += counts[idx];
    }
  }
  if (t == 1023) row_ptr[cN] = part[1023];
}

// descending-degree counting sort: perm[pos] = node, heaviest first.
// Only changes which wave handles which node; results are value-identical.
__global__ void k_dsort(const int* counts, int* perm) {
  __shared__ int bins[64], boff[64];
  int t = threadIdx.x;
  if (t < 64) bins[t] = 0;
  __syncthreads();
  for (int n = t; n < cN; n += 1024) {
    int d = counts[n];
    if (d > 63) d = 63;
    atomicAdd(&bins[63 - d], 1);
  }
  __syncthreads();
  if (t == 0) {
    int acc = 0;
    for (int i = 0; i < 64; i++) {
      boff[i] = acc;
      acc += bins[i];
    }
  }
  __syncthreads();
  for (int n = t; n < cN; n += 1024) {
    int d = counts[n];
    if (d > 63) d = 63;
    int pos = atomicAdd(&boff[63 - d], 1);
    perm[pos] = n;
  }
}

__global__ void k_scatter(const int* src, const int* dst, fp ea, fp w1, fp b1, fp w2, fp b2,
                          int* cursor, int* esrc, float* gcsr) {
  int e = blockIdx.x * 256 + threadIdx.x;
  if (e >= cE) return;
  float a0 = ea[e * 4 + 0], a1 = ea[e * 4 + 1], a2 = ea[e * 4 + 2], a3 = ea[e * 4 + 3];
  float acc = b2[0];
#pragma unroll
  for (int j = 0; j < 16; j++) {
    float tv = b1[j] + a0 * w1[j] + a1 * w1[16 + j] + a2 * w1[32 + j] + a3 * w1[48 + j];
    acc += ftanh(tv) * w2[j];
  }
  float g = 1.f / (1.f + __expf(-acc));
  int p = atomicAdd(&cursor[dst[e]], 1);
  esrc[p] = src[e];
  gcsr[p] = g;
}

// ---------------- setup: counts zero + h init + weight prepack ----------------
constexpr int cWTOT = 128 * 160 + 64 * 128 + 64 * 64 + 3 * 64 * 64;  // 45056
__global__ void k_setup(int* counts, float* h, u16* h_bf, fp h0, fp W_tau, fp W_g, fp W_enc,
                        fp W_lt, fp W_hop, u16* Wtg, u16* Wenc, u16* Wlt, u16* Whop) {
  int i = blockIdx.x * 256 + threadIdx.x;
  if (i < cN) counts[i] = 0;
  if (i < cBNH) {
    float v = h0[i & 63];
    h[i] = v;
    h_bf[i] = f2b(v);
  }
  if (i < 128 * 160) {
    int col = i / 160, k = i - col * 160;
    float v = 0.f;
    if (k < 133) v = (col < 64) ? W_tau[k * 64 + col] : W_g[k * 64 + (col - 64)];
    Wtg[i] = f2b(v);
  } else if (i < 128 * 160 + 64 * 128) {
    int i2 = i - 128 * 160;
    int col = i2 / 128, k = i2 - col * 128;
    Wenc[i2] = f2b(W_enc[k * 64 + col]);
  } else if (i < 128 * 160 + 64 * 128 + 64 * 64) {
    int i3 = i - 128 * 160 - 64 * 128;
    int col = i3 / 64, k = i3 - col * 64;
    Wlt[i3] = f2b(W_lt[k * 64 + col]);
  } else if (i < cWTOT) {
    int i4 = i - 128 * 160 - 64 * 128 - 64 * 64;
    int hop = i4 / 4096, rem = i4 - hop * 4096;
    int col = rem / 64, k = rem - col * 64;
    Whop[i4] = f2b(W_hop[hop * 4096 + k * 64 + col]);
  }
}

// ---------------- hop matvec: MFMA, bf16 in/out (used once, t=0 hop0) ----------------
__global__ __launch_bounds__(256) void k_hop_mat_m(const u16* vin_bf, const u16* Wh, fp avs,
                                                   fp avd, u16* hw_bf, float* ssrc,
                                                   float* sdst) {
  __shared__ u16 tin[64 * 72];
  __shared__ u16 thw[64 * 72];
  __shared__ float red1[4][64], red2[4][64];
  int tid = threadIdx.x, w = tid >> 6, lane = tid & 63;
  int quad = lane >> 4, l15 = lane & 15;
  int base = blockIdx.x * 64;
  {
    int tn = tid >> 2, cs = (tid & 3) * 16;
    int gn = base + tn;
    if (gn >= cBN) gn = cBN - 1;
    const short8* src = (const short8*)(vin_bf + (size_t)gn * 64 + cs);
    *(short8*)(tin + tn * 72 + cs) = src[0];
    *(short8*)(tin + tn * 72 + cs + 8) = src[1];
  }
  __syncthreads();
  f32x4 acc[4];
#pragma unroll
  for (int mt = 0; mt < 4; mt++) acc[mt] = (f32x4){0.f, 0.f, 0.f, 0.f};
#pragma unroll
  for (int ks = 0; ks < 2; ks++) {
    short8 bfr = *(const short8*)(Wh + (16 * w + l15) * 64 + ks * 32 + quad * 8);
#pragma unroll
    for (int mt = 0; mt < 4; mt++) {
      short8 afr = *(const short8*)(tin + (mt * 16 + l15) * 72 + ks * 32 + quad * 8);
      acc[mt] = __builtin_amdgcn_mfma_f32_16x16x32_bf16(afr, bfr, acc[mt], 0, 0, 0);
    }
  }
  int col = 16 * w + l15;
#pragma unroll
  for (int mt = 0; mt < 4; mt++) {
#pragma unroll
    for (int r = 0; r < 4; r++) {
      thw[(mt * 16 + quad * 4 + r) * 72 + col] = f2b(acc[mt][r]);
    }
  }
  __syncthreads();
  {
    float r1 = 0.f, r2 = 0.f;
#pragma unroll
    for (int c = 0; c < 16; c++) {
      float v = b2f(thw[lane * 72 + 16 * w + c]);
      r1 += v * avs[16 * w + c];
      r2 += v * avd[16 * w + c];
    }
    red1[w][lane] = r1;
    red2[w][lane] = r2;
  }
  __syncthreads();
  if (w == 0 && base + lane < cBN) {
    ssrc[base + lane] = red1[0][lane] + red1[1][lane] + red1[2][lane] + red1[3][lane];
    sdst[base + lane] = red2[0][lane] + red2[1][lane] + red2[2][lane] + red2[3][lane];
  }
  {
    int tn = tid >> 2, cs = (tid & 3) * 16;
    int gn = base + tn;
    if (gn < cBN) {
      short8* dst = (short8*)(hw_bf + (size_t)gn * 64 + cs);
      dst[0] = *(const short8*)(thw + tn * 72 + cs);
      dst[1] = *(const short8*)(thw + tn * 72 + cs + 8);
    }
  }
}

// ---------------- larval gather: agg_bf[u] = sum_e g[e] * h[src[e]] ----------------
// Working set = h_bf (2.56MB) only -> L2-resident. Same per-edge order as before.
__global__ __launch_bounds__(256) void k_larval(const u16* h_bf, const int* row_ptr,
                                                const int* esrc, const float* gcsr,
                                                const int* perm, u16* agg_bf) {
  int w = threadIdx.x >> 6, lane = threadIdx.x & 63;
  int q = lane >> 4, ql = lane & 15;
  int i = blockIdx.x * 4 + w;
  int n = perm[i >> 1];
  int b = i & 1;
  int u = b * cN + n;
  int r0 = row_ptr[n], r1e = row_ptr[n + 1];
  const u16* hb = h_bf + (size_t)b * cN * 64;
  float la0 = 0.f, la1 = 0.f, la2 = 0.f, la3 = 0.f;
  for (int e0 = r0; e0 < r1e; e0 += 64) {
    int e = e0 + lane;
    bool vld = e < r1e;
    int s = vld ? esrc[e] : 0;
    float g = vld ? gcsr[e] : 0.f;
    int cnt = min(64, r1e - e0);
    for (int j = 0; j < cnt; j += 8) {
      int sj1 = __shfl(s, j + q, 64);
      float gj1 = __shfl(g, j + q, 64);
      int sj2 = __shfl(s, j + 4 + q, 64);
      float gj2 = __shfl(g, j + 4 + q, 64);
      uint2 d1 = *(const uint2*)(hb + (size_t)sj1 * 64 + ql * 4);
      uint2 d2 = *(const uint2*)(hb + (size_t)sj2 * 64 + ql * 4);
      la0 += gj1 * __uint_as_float(d1.x << 16);
      la1 += gj1 * __uint_as_float(d1.x & 0xffff0000u);
      la2 += gj1 * __uint_as_float(d1.y << 16);
      la3 += gj1 * __uint_as_float(d1.y & 0xffff0000u);
      la0 += gj2 * __uint_as_float(d2.x << 16);
      la1 += gj2 * __uint_as_float(d2.x & 0xffff0000u);
      la2 += gj2 * __uint_as_float(d2.y << 16);
      la3 += gj2 * __uint_as_float(d2.y & 0xffff0000u);
    }
  }
  la0 += __shfl_xor(la0, 16); la0 += __shfl_xor(la0, 32);
  la1 += __shfl_xor(la1, 16); la1 += __shfl_xor(la1, 32);
  la2 += __shfl_xor(la2, 16); la2 += __shfl_xor(la2, 32);
  la3 += __shfl_xor(la3, 16); la3 += __shfl_xor(la3, 32);
  if (q == 0) {
    uint2 ga;
    ga.x = ((unsigned)f2b(la1) << 16) | (unsigned)f2b(la0);
    ga.y = ((unsigned)f2b(la3) << 16) | (unsigned)f2b(la2);
    *(uint2*)(agg_bf + (size_t)u * 64 + ql * 4) = ga;
  }
}

// ---------------- hop aggregate + fused next-hop matvec (templated per hop) ------------
// Wave w handles (b = i&1, n = perm[i>>1]) — batch-paired, degree-sorted.
// Gather working set = hw_bf (2.56MB) only. 2x-unrolled gather loop.
template <int HOP>
__global__ __launch_bounds__(256) void k_hop_agg(
    const u16* hw_bf, const float* ssrc, const float* sdst, const int* row_ptr,
    const int* esrc, float* khsum, const int* perm, const u16* Wnext, fp avs_n, fp avd_n,
    u16* hw_out, float* ssrc_out, float* sdst_out) {
  __shared__ u16 cur16[16 * 72];  // bf16 A-tile for fused matvec (rows 0-3 valid)
  __shared__ u16 thw[4 * 64];     // fused matvec output rows
  int w = threadIdx.x >> 6, lane = threadIdx.x & 63;
  int q = lane >> 4, ql = lane & 15;
  int i = blockIdx.x * 4 + w;
  int n = perm[i >> 1];
  int b = i & 1;
  int u = b * cN + n;
  int r0 = row_ptr[n], r1e = row_ptr[n + 1];
  const float* sb = ssrc + (size_t)b * cN;
  float sd = sdst[u];
  float den = 0.f;
  float num0 = 0.f, num1 = 0.f, num2 = 0.f, num3 = 0.f;
  const u16* hwb = hw_bf + (size_t)b * cN * 64;
  for (int e0 = r0; e0 < r1e; e0 += 64) {
    int e = e0 + lane;
    bool vld = e < r1e;
    int s = vld ? esrc[e] : 0;
    float a = 0.f;
    if (vld) {
      float ev = sb[s] + sd;
      ev = ev > 0.f ? ev : 0.2f * ev;
      a = __expf(ev);  // |ev| small; softmax shift-invariant
    }
    den += a;
    int cnt = min(64, r1e - e0);
    for (int j = 0; j < cnt; j += 8) {
      // quarter q handles edges j+q and j+4+q (a=0 pads tails); lane covers cols ql*4..+3
      int sj1 = __shfl(s, j + q, 64);
      float aj1 = __shfl(a, j + q, 64);
      int sj2 = __shfl(s, j + 4 + q, 64);
      float aj2 = __shfl(a, j + 4 + q, 64);
      uint2 d1 = *(const uint2*)(hwb + (size_t)sj1 * 64 + ql * 4);
      uint2 d2 = *(const uint2*)(hwb + (size_t)sj2 * 64 + ql * 4);
      num0 += aj1 * __uint_as_float(d1.x << 16);
      num1 += aj1 * __uint_as_float(d1.x & 0xffff0000u);
      num2 += aj1 * __uint_as_float(d1.y << 16);
      num3 += aj1 * __uint_as_float(d1.y & 0xffff0000u);
      num0 += aj2 * __uint_as_float(d2.x << 16);
      num1 += aj2 * __uint_as_float(d2.x & 0xffff0000u);
      num2 += aj2 * __uint_as_float(d2.y << 16);
      num3 += aj2 * __uint_as_float(d2.y & 0xffff0000u);
    }
  }
  den = wsum(den);
  num0 += __shfl_xor(num0, 16); num0 += __shfl_xor(num0, 32);
  num1 += __shfl_xor(num1, 16); num1 += __shfl_xor(num1, 32);
  num2 += __shfl_xor(num2, 16); num2 += __shfl_xor(num2, 32);
  num3 += __shfl_xor(num3, 16); num3 += __shfl_xor(num3, 32);
  if (q == 0) {
    float inv = 1.f / (den + 1e-16f);
    float c0 = num0 * inv, c1 = num1 * inv, c2 = num2 * inv, c3 = num3 * inv;
    size_t ni = (size_t)u * 64 + ql * 4;
    if constexpr (HOP < 2) {
      uint2 pk;
      pk.x = ((unsigned)f2b(c1) << 16) | (unsigned)f2b(c0);
      pk.y = ((unsigned)f2b(c3) << 16) | (unsigned)f2b(c2);
      *(uint2*)(cur16 + w * 72 + ql * 4) = pk;  // LDS, not global
    }
    float4* kp = (float4*)(khsum + ni);
    if constexpr (HOP == 0) {
      float4 kv;
      kv.x = c0; kv.y = c1; kv.z = c2; kv.w = c3;
      *kp = kv;
    } else {
      float4 kv = *kp;
      kv.x += c0; kv.y += c1; kv.z += c2; kv.w += c3;
      *kp = kv;
    }
  }
  // ---- fused next-hop matvec: hw_out[u] = cur[u] @ Wnext; ssrc/sdst for next hop ----
  if constexpr (HOP < 2) {
    __syncthreads();
    f32x4 hacc = (f32x4){0.f, 0.f, 0.f, 0.f};
#pragma unroll
    for (int ks = 0; ks < 2; ks++) {
      short8 bfr = *(const short8*)(Wnext + (16 * w + ql) * 64 + ks * 32 + q * 8);
      short8 afr = *(const short8*)(cur16 + ql * 72 + ks * 32 + q * 8);
      hacc = __builtin_amdgcn_mfma_f32_16x16x32_bf16(afr, bfr, hacc, 0, 0, 0);
    }
    int col = 16 * w + ql;
    if (q == 0) {  // rows 0-3 = this block's 4 (b,n) waves
#pragma unroll
      for (int r = 0; r < 4; r++) thw[r * 64 + col] = f2b(hacc[r]);
    }
    __syncthreads();
    float v = b2f(thw[w * 64 + lane]);
    float r1 = wsum(v * avs_n[lane]);
    float r2 = wsum(v * avd_n[lane]);
    if (lane == 0) {
      ssrc_out[u] = r1;
      sdst_out[u] = r2;
    }
    if (q == 0) {
      *(uint2*)(hw_out + (size_t)u * 64 + ql * 4) = *(const uint2*)(thw + w * 64 + ql * 4);
    }
  }
}

// ---------------- MFMA mega-kernel: p-GEMM + tau/g GEMM + u GEMM + cell + next hop0 mat --
__global__ __launch_bounds__(256) void k_mega(fp x, int t, float* h_nm, u16* h_bf,
                                              const float* khsum, const u16* agg_bf,
                                              const int* row_ptr, const u16* Wtg,
                                              const u16* Wenc, const u16* Wlt, const u16* Whop0,
                                              fp avs0, fp avd0, u16* hw_bf, float* ssrc,
                                              float* sdst, fp b_tau, fp b_g, fp b_enc, fp gamma,
                                              fp beta, fp c_enc, fp cdec, fp W_dec, fp b_dec,
                                              float* out) {
  __shared__ __align__(16) char lds[59904];
  u16* tz = (u16*)lds;                  // [64][168] bf16
  u16* tphi = (u16*)(lds + 30720);      // [64][136] bf16
  float* tgu = (float*)lds;             // [64][197] fp32 overlay (after GEMMs)
  u16* tzh = (u16*)lds;                 // [64][72] bf16 (tail overlay)
  u16* thw2 = (u16*)(lds + 10240);      // [64][72] bf16 (tail overlay)
  float* sx = (float*)(lds + 50432);
  float* redm = (float*)(lds + 54784);  // [4][64]
  float* redv = redm + 256;             // [4][64]
  float* redp = redv + 256;             // [4][3][64]
  int tid = threadIdx.x;
  int w = tid >> 6, lane = tid & 63;
  int quad = lane >> 4, l15 = lane & 15;
  int base = blockIdx.x * 64;
  {
    int tn = tid >> 2, f4 = (tid & 3) * 4;
    int gn = base + tn;
    if (gn >= cBN) gn = cBN - 1;
    int gb = gn / cN, gnn = gn - gb * cN;
    float4 xv = *(const float4*)(x + (((size_t)gb * cT + t) * cN + gnn) * cF + f4);
    sx[tn * 17 + f4 + 0] = xv.x;
    sx[tn * 17 + f4 + 1] = xv.y;
    sx[tn * 17 + f4 + 2] = xv.z;
    sx[tn * 17 + f4 + 3] = xv.w;
    int f0 = (tid & 3) * 16;
    const short8* hs = (const short8*)(h_bf + (size_t)gn * 64 + f0);
    *(short8*)(tz + tn * 168 + f0) = hs[0];
    *(short8*)(tz + tn * 168 + f0 + 8) = hs[1];
  }
  for (int i = tid; i < 64 * 27; i += 256) {
    int nn2 = i / 27;
    tz[nn2 * 168 + 133 + (i - nn2 * 27)] = 0;
  }
  __syncthreads();
  for (int i = tid; i < 320; i += 256) {
    int j = i >> 6, n2 = i & 63;
    tz[n2 * 168 + 64 + j] = f2b(sx[n2 * 17 + 8 + j]);
  }
  // phi via RBF recurrence: per (node,f) bundle, 2 exps for 8 bases
  {
    float ec0 = c_enc[0], ec7 = c_enc[7];
    float inv_e = 7.f / (ec7 - ec0);
    for (int i = tid; i < 64 * 16; i += 256) {
      int n2 = i >> 4, f = i & 15;
      float d0 = (sx[n2 * 17 + f] - ec0) * inv_e;
      float phi = __expf(-d0 * d0);
      float r = __expf(2.f * d0 - 1.f);
      u16* dst = tphi + n2 * 136 + f * 8;
#pragma unroll
      for (int cb = 0; cb < 8; cb++) {
        dst[cb] = f2b(phi);
        phi *= r;
        r *= cEXPM2;
      }
    }
  }
  __syncthreads();
  // G2: u = phi @ Wenc
  f32x4 accU[4];
#pragma unroll
  for (int mt = 0; mt < 4; mt++) accU[mt] = (f32x4){0.f, 0.f, 0.f, 0.f};
#pragma unroll
  for (int ks = 0; ks < 4; ks++) {
    short8 bfr = *(const short8*)(Wenc + (16 * w + l15) * 128 + ks * 32 + quad * 8);
#pragma unroll
    for (int mt = 0; mt < 4; mt++) {
      short8 afr = *(const short8*)(tphi + (mt * 16 + l15) * 136 + ks * 32 + quad * 8);
      accU[mt] = __builtin_amdgcn_mfma_f32_16x16x32_bf16(afr, bfr, accU[mt], 0, 0, 0);
    }
  }
  // G0: plt = agg @ Wlt -> p rows into tz
  {
    f32x4 accP[4];
#pragma unroll
    for (int mt = 0; mt < 4; mt++) accP[mt] = (f32x4){0.f, 0.f, 0.f, 0.f};
#pragma unroll
    for (int ks = 0; ks < 2; ks++) {
      short8 bfr = *(const short8*)(Wlt + (16 * w + l15) * 64 + ks * 32 + quad * 8);
#pragma unroll
      for (int mt = 0; mt < 4; mt++) {
        int gn = base + mt * 16 + l15;
        if (gn >= cBN) gn = cBN - 1;
        short8 afr = *(const short8*)(agg_bf + (size_t)gn * 64 + ks * 32 + quad * 8);
        accP[mt] = __builtin_amdgcn_mfma_f32_16x16x32_bf16(afr, bfr, accP[mt], 0, 0, 0);
      }
    }
    int colP = 16 * w + l15;
#pragma unroll
    for (int mt = 0; mt < 4; mt++) {
#pragma unroll
      for (int r = 0; r < 4; r++) {
        int nl = mt * 16 + quad * 4 + r;
        int gn = base + nl;
        int gnc = gn < cBN ? gn : cBN - 1;
        int bB = gnc / cN, nn = gnc - bB * cN;
        float deg = (float)(row_ptr[nn + 1] - row_ptr[nn]);
        float pv = khsum[(size_t)gnc * 64 + colP] * (1.f / 3.f) + accP[mt][r] / (deg + 1.f);
        tz[nl * 168 + 69 + colP] = f2b(pv);
      }
    }
  }
  __syncthreads();
  // G1: [tau|g] = z @ Wtg (K=160)
  f32x4 accT[8];
#pragma unroll
  for (int i = 0; i < 8; i++) accT[i] = (f32x4){0.f, 0.f, 0.f, 0.f};
#pragma unroll
  for (int ks = 0; ks < 5; ks++) {
    short8 b0 = *(const short8*)(Wtg + (32 * w + l15) * 160 + ks * 32 + quad * 8);
    short8 b1 = *(const short8*)(Wtg + (32 * w + 16 + l15) * 160 + ks * 32 + quad * 8);
#pragma unroll
    for (int mt = 0; mt < 4; mt++) {
      short8 afr = *(const short8*)(tz + (mt * 16 + l15) * 168 + ks * 32 + quad * 8);
      accT[mt * 2 + 0] =
          __builtin_amdgcn_mfma_f32_16x16x32_bf16(afr, b0, accT[mt * 2 + 0], 0, 0, 0);
      accT[mt * 2 + 1] =
          __builtin_amdgcn_mfma_f32_16x16x32_bf16(afr, b1, accT[mt * 2 + 1], 0, 0, 0);
    }
  }
  __syncthreads();  // tz dead; tgu overlay
#pragma unroll
  for (int mt = 0; mt < 4; mt++) {
#pragma unroll
    for (int ntl = 0; ntl < 2; ntl++) {
#pragma unroll
      for (int r = 0; r < 4; r++) {
        int nl = mt * 16 + quad * 4 + r;
        tgu[nl * 197 + 32 * w + ntl * 16 + l15] = accT[mt * 2 + ntl][r];
      }
    }
#pragma unroll
    for (int r = 0; r < 4; r++) {
      int nl = mt * 16 + quad * 4 + r;
      tgu[nl * 197 + 128 + 16 * w + l15] = accU[mt][r];
    }
  }
  __syncthreads();
  // epilogue: thread = node lane, col chunk c0
  int c0 = __builtin_amdgcn_readfirstlane(w * 16);
  int node = base + lane;
  int ngc = node < cBN ? node : cBN - 1;
  int bb = ngc / cN, nn = ngc - bb * cN;
  float hv[16];
  {
    const float4* hp = (const float4*)(h_nm + (size_t)ngc * 64 + c0);
#pragma unroll
    for (int q = 0; q < 4; q++) {
      float4 v = hp[q];
      hv[q * 4 + 0] = v.x; hv[q * 4 + 1] = v.y; hv[q * 4 + 2] = v.z; hv[q * 4 + 3] = v.w;
    }
  }
  float acc[16];
  float pm = 0.f;
#pragma unroll
  for (int c = 0; c < 16; c++) {
    float at = tgu[lane * 197 + c0 + c] + b_tau[c0 + c];
    float ag = tgu[lane * 197 + 64 + c0 + c] + b_g[c0 + c];
    float tau = 1.f + 9.f / (1.f + __expf(-at));
    float g = ftanh(ag);
    float v = hv[c] + 0.25f * (g - hv[c]) / tau;
    acc[c] = v;
    pm += v;
  }
  redm[w * 64 + lane] = pm;
  __syncthreads();
  float mu = (redm[lane] + redm[64 + lane] + redm[128 + lane] + redm[192 + lane]) * (1.f / 64.f);
  float pv = 0.f;
#pragma unroll
  for (int c = 0; c < 16; c++) {
    float d = acc[c] - mu;
    pv += d * d;
  }
  redv[w * 64 + lane] = pv;
  __syncthreads();
  float var = (redv[lane] + redv[64 + lane] + redv[128 + lane] + redv[192 + lane]) * (1.f / 64.f);
  float rstd = rsqrtf(var + 1e-5f);
#pragma unroll
  for (int c = 0; c < 16; c++) {
    acc[c] = (acc[c] - mu) * rstd * gamma[c0 + c] + beta[c0 + c] +
             tgu[lane * 197 + 128 + c0 + c] + b_enc[c0 + c];
  }
  if (node < cBN) {
    float4* hp = (float4*)(h_nm + (size_t)ngc * 64 + c0);
#pragma unroll
    for (int q = 0; q < 4; q++) {
      float4 v;
      v.x = acc[q * 4 + 0]; v.y = acc[q * 4 + 1]; v.z = acc[q * 4 + 2]; v.w = acc[q * 4 + 3];
      hp[q] = v;
    }
    unsigned* bp = (unsigned*)(h_bf + (size_t)ngc * 64 + c0);
#pragma unroll
    for (int q = 0; q < 8; q++) {
      unsigned lo = f2b(acc[q * 2 + 0]);
      unsigned hi = f2b(acc[q * 2 + 1]);
      bp[q] = (hi << 16) | lo;
    }
  }
  // decoder fastkan (RBF recurrence: 2 exps per col) + softplus
  float dc0 = cdec[0], dc7 = cdec[7];
  float inv_d = 7.f / (dc7 - dc0);
  float p0 = 0.f, p1 = 0.f, p2 = 0.f;
#pragma unroll
  for (int c = 0; c < 16; c++) {
    float d0 = (acc[c] - dc0) * inv_d;
    float ph = __expf(-d0 * d0);
    float r = __expf(2.f * d0 - 1.f);
    const float* Wd = W_dec + (c0 + c) * 24;
#pragma unroll
    for (int j = 0; j < 8; j++) {
      p0 += ph * Wd[j * 3];
      p1 += ph * Wd[j * 3 + 1];
      p2 += ph * Wd[j * 3 + 2];
      ph *= r;
      r *= cEXPM2;
    }
  }
  redp[(w * 3 + 0) * 64 + lane] = p0;
  redp[(w * 3 + 1) * 64 + lane] = p1;
  redp[(w * 3 + 2) * 64 + lane] = p2;
  __syncthreads();  // also: all tgu reads complete -> tail overlay safe
  if (w == 0 && node < cBN) {
    float v0 = redp[0 * 64 + lane] + redp[3 * 64 + lane] + redp[6 * 64 + lane] +
               redp[9 * 64 + lane] + b_dec[0];
    float v1 = redp[1 * 64 + lane] + redp[4 * 64 + lane] + redp[7 * 64 + lane] +
               redp[10 * 64 + lane] + b_dec[1];
    float v2 = redp[2 * 64 + lane] + redp[5 * 64 + lane] + redp[8 * 64 + lane] +
               redp[11 * 64 + lane] + b_dec[2];
    size_t ob = (((size_t)bb * cT + t) * cN + nn) * 3;
    out[ob] = fmaxf(v0, 0.f) + log1pf(__expf(-fabsf(v0)));
    out[ob + 1] = fmaxf(v1, 0.f) + log1pf(__expf(-fabsf(v1)));
    out[ob + 2] = fmaxf(v2, 0.f) + log1pf(__expf(-fabsf(v2)));
  }
  // ---- fused tail: next-step hop0 matvec (node-local: uses just-computed h) ----
#pragma unroll
  for (int c = 0; c < 16; c++) tzh[lane * 72 + c0 + c] = f2b(acc[c]);
  __syncthreads();
  f32x4 hacc[4];
#pragma unroll
  for (int mt = 0; mt < 4; mt++) hacc[mt] = (f32x4){0.f, 0.f, 0.f, 0.f};
#pragma unroll
  for (int ks = 0; ks < 2; ks++) {
    short8 bfr = *(const short8*)(Whop0 + (16 * w + l15) * 64 + ks * 32 + quad * 8);
#pragma unroll
    for (int mt = 0; mt < 4; mt++) {
      short8 afr = *(const short8*)(tzh + (mt * 16 + l15) * 72 + ks * 32 + quad * 8);
      hacc[mt] = __builtin_amdgcn_mfma_f32_16x16x32_bf16(afr, bfr, hacc[mt], 0, 0, 0);
    }
  }
  int colh = 16 * w + l15;
#pragma unroll
  for (int mt = 0; mt < 4; mt++) {
#pragma unroll
    for (int r = 0; r < 4; r++) {
      thw2[(mt * 16 + quad * 4 + r) * 72 + colh] = f2b(hacc[mt][r]);
    }
  }
  __syncthreads();
  {
    float r1 = 0.f, r2 = 0.f;
#pragma unroll
    for (int c = 0; c < 16; c++) {
      float v = b2f(thw2[lane * 72 + 16 * w + c]);
      r1 += v * avs0[16 * w + c];
      r2 += v * avd0[16 * w + c];
    }
    redm[w * 64 + lane] = r1;
    redv[w * 64 + lane] = r2;
  }
  __syncthreads();
  if (w == 0 && node < cBN) {
    ssrc[node] = redm[lane] + redm[64 + lane] + redm[128 + lane] + redm[192 + lane];
    sdst[node] = redv[lane] + redv[64 + lane] + redv[128 + lane] + redv[192 + lane];
  }
  {
    int tn = tid >> 2, cs = (tid & 3) * 16;
    int gn = base + tn;
    if (gn < cBN) {
      short8* dst = (short8*)(hw_bf + (size_t)gn * 64 + cs);
      dst[0] = *(const short8*)(thw2 + tn * 72 + cs);
      dst[1] = *(const short8*)(thw2 + tn * 72 + cs + 8);
    }
  }
}

extern "C" void kernel_launch(void* const* d_in, const int* in_sizes, int n_in, void* d_out,
                              int out_size, void* d_ws, size_t ws_size, hipStream_t stream) {
  fp x = (fp)d_in[0];
  fp edge_attr = (fp)d_in[1];
  fp c_enc = (fp)d_in[2];
  fp W_enc = (fp)d_in[3];
  fp b_enc = (fp)d_in[4];
  fp W_hop = (fp)d_in[5];
  fp a_src = (fp)d_in[6];
  fp a_dst = (fp)d_in[7];
  fp w_lt1 = (fp)d_in[8];
  fp b_lt1 = (fp)d_in[9];
  fp w_lt2 = (fp)d_in[10];
  fp b_lt2 = (fp)d_in[11];
  fp W_lt = (fp)d_in[12];
  fp W_tau = (fp)d_in[13];
  fp b_tau = (fp)d_in[14];
  fp W_g = (fp)d_in[15];
  fp b_g = (fp)d_in[16];
  fp gamma = (fp)d_in[17];
  fp beta = (fp)d_in[18];
  fp c_dec = (fp)d_in[19];
  fp W_dec = (fp)d_in[20];
  fp b_dec = (fp)d_in[21];
  fp h0 = (fp)d_in[22];
  const int* eidx = (const int*)d_in[23];
  const int* esrc_in = eidx;
  const int* edst_in = eidx + cE;

  float* fws = (float*)d_ws;
  float* h_nm = fws;   fws += cBNH;
  float* khsum = fws;  fws += cBNH;
  float* ssrc = fws;   fws += cBN;
  float* sdst = fws;   fws += cBN;
  float* ssrc2 = fws;  fws += cBN;
  float* sdst2 = fws;  fws += cBN;
  float* gcsr = fws;   fws += cE;
  u16* h_bf = (u16*)fws;    fws += cBNH / 2;
  u16* hw_bf = (u16*)fws;   fws += cBNH / 2;
  u16* hw_bf2 = (u16*)fws;  fws += cBNH / 2;
  u16* agg_bf = (u16*)fws;  fws += cBNH / 2;
  u16* Wtg = (u16*)fws;   fws += (128 * 160) / 2;
  u16* Wenc = (u16*)fws;  fws += (64 * 128) / 2;
  u16* Wlt = (u16*)fws;   fws += (64 * 64) / 2;
  u16* Whop = (u16*)fws;  fws += (3 * 64 * 64) / 2;
  int* iws = (int*)fws;
  int* esrc = iws;    iws += cE;
  int* row_ptr = iws; iws += cN + 1;
  int* cursor = iws;  iws += cN;
  int* counts = iws;  iws += cN;
  int* perm = iws;    iws += cN;

  k_setup<<<(cBNH + 255) / 256, 256, 0, stream>>>(counts, h_nm, h_bf, h0, W_tau, W_g, W_enc,
                                                  W_lt, W_hop, Wtg, Wenc, Wlt, Whop);
  k_count<<<(cE + 255) / 256, 256, 0, stream>>>(edst_in, counts);
  k_scan<<<1, 1024, 0, stream>>>(counts, row_ptr, cursor);
  k_dsort<<<1, 1024, 0, stream>>>(counts, perm);
  k_scatter<<<(cE + 255) / 256, 256, 0, stream>>>(esrc_in, edst_in, edge_attr, w_lt1, b_lt1,
                                                  w_lt2, b_lt2, cursor, esrc, gcsr);
  // initial hop0 matvec for t=0 (later steps get it fused into k_mega's tail)
  k_hop_mat_m<<<NBLK, 256, 0, stream>>>(h_bf, Whop, a_src, a_dst, hw_bf, ssrc, sdst);

  for (int t = 0; t < cT; t++) {
    // larval gather (h_bf working set only; independent of attention hops)
    k_larval<<<cBN / 4, 256, 0, stream>>>(h_bf, row_ptr, esrc, gcsr, perm, agg_bf);
    // hop0: read set0, fused mat writes set1
    k_hop_agg<0><<<cBN / 4, 256, 0, stream>>>(hw_bf, ssrc, sdst, row_ptr, esrc, khsum, perm,
                                              Whop + 4096, a_src + cH, a_dst + cH, hw_bf2,
                                              ssrc2, sdst2);
    // hop1: read set1, fused mat writes set0
    k_hop_agg<1><<<cBN / 4, 256, 0, stream>>>(hw_bf2, ssrc2, sdst2, row_ptr, esrc, khsum, perm,
                                              Whop + 2 * 4096, a_src + 2 * cH, a_dst + 2 * cH,
                                              hw_bf, ssrc, sdst);
    // hop2: read set0, no fused mat
    k_hop_agg<2><<<cBN / 4, 256, 0, stream>>>(hw_bf, ssrc, sdst, row_ptr, esrc, khsum, perm,
                                              nullptr, nullptr, nullptr, nullptr, nullptr,
                                              nullptr);
    k_mega<<<NBLK, 256, 0, stream>>>(x, t, h_nm, h_bf, khsum, agg_bf, row_ptr, Wtg, Wenc, Wlt,
                                     Whop, a_src, a_dst, hw_bf, ssrc, sdst, b_tau, b_g, b_enc,
                                     gamma, beta, c_enc, c_dec, W_dec, b_dec, (float*)d_out);
  }
}

// Round 6
// 306.674 us; speedup vs baseline: 1.2469x; 1.2469x over previous
//
#include <hip/hip_runtime.h>
#include <hip/hip_bf16.h>
#include <math.h>

// SeaLiceGLKAN — fp32 in/out. R20: quarter-wave gather — each 16-lane quarter
// owns one (batch,node) pair (2 sorted-adjacent nodes x 2 batches per wave).
// Lane-private column accumulators kill all cross-lane num reductions; larval
// fused back into hop0 (shares shfl'd src index); fused next-hop matvec now a
// full 16-row MFMA. 12 gather launches/step-loop instead of 16.

constexpr int cB = 2, cT = 4, cN = 10000, cF = 16, cH = 64, cE = 160000, cK = 3;
constexpr int cBN = cB * cN;    // 20000
constexpr int cBNH = cBN * cH;  // 1,280,000
constexpr int NBLK = (cBN + 63) / 64;   // 313 nodegroups of 64
constexpr int ABLK = cBN / 16;          // 1250 agg blocks (16 pairs each)

typedef const float* fp;
typedef short short8 __attribute__((ext_vector_type(8)));
typedef float f32x4 __attribute__((ext_vector_type(4)));
typedef unsigned short u16;

constexpr float cEXPM2 = 0.13533528323661270f;  // exp(-2)

__device__ __forceinline__ float wsum(float v) {
#pragma unroll
  for (int o = 1; o < 64; o <<= 1) v += __shfl_xor(v, o, 64);
  return v;
}
__device__ __forceinline__ u16 f2b(float f) {  // fp32 -> bf16 bits (RNE)
  unsigned u = __float_as_uint(f);
  u += 0x7FFFu + ((u >> 16) & 1u);
  return (u16)(u >> 16);
}
__device__ __forceinline__ float b2f(u16 b) { return __uint_as_float(((unsigned)b) << 16); }
__device__ __forceinline__ float bl(unsigned x) { return __uint_as_float(x << 16); }
__device__ __forceinline__ float bh(unsigned x) { return __uint_as_float(x & 0xffff0000u); }
__device__ __forceinline__ float ftanh(float x) {
  float e = __expf(2.f * x);
  return (e - 1.f) / (e + 1.f);
}

// ---------------- CSR build ----------------
__global__ void k_count(const int* dst, int* counts) {
  int e = blockIdx.x * 256 + threadIdx.x;
  if (e < cE) atomicAdd(&counts[dst[e]], 1);
}

__global__ void k_scan(const int* counts, int* row_ptr, int* cursor) {
  __shared__ int part[1024];
  int t = threadIdx.x;
  const int CH = (cN + 1023) / 1024;  // 10
  int s = 0;
  for (int i = 0; i < CH; i++) {
    int idx = t * CH + i;
    if (idx < cN) s += counts[idx];
  }
  part[t] = s;
  __syncthreads();
  for (int off = 1; off < 1024; off <<= 1) {
    int v = (t >= off) ? part[t - off] : 0;
    __syncthreads();
    part[t] += v;
    __syncthreads();
  }
  int excl = (t == 0) ? 0 : part[t - 1];
  for (int i = 0; i < CH; i++) {
    int idx = t * CH + i;
    if (idx < cN) {
      row_ptr[idx] = excl;
      cursor[idx] = excl;
      excl += counts[idx];
    }
  }
  if (t == 1023) row_ptr[cN] = part[1023];
}

// descending-degree counting sort: perm[pos] = node, heaviest first.
__global__ void k_dsort(const int* counts, int* perm) {
  __shared__ int bins[64], boff[64];
  int t = threadIdx.x;
  if (t < 64) bins[t] = 0;
  __syncthreads();
  for (int n = t; n < cN; n += 1024) {
    int d = counts[n];
    if (d > 63) d = 63;
    atomicAdd(&bins[63 - d], 1);
  }
  __syncthreads();
  if (t == 0) {
    int acc = 0;
    for (int i = 0; i < 64; i++) {
      boff[i] = acc;
      acc += bins[i];
    }
  }
  __syncthreads();
  for (int n = t; n < cN; n += 1024) {
    int d = counts[n];
    if (d > 63) d = 63;
    int pos = atomicAdd(&boff[63 - d], 1);
    perm[pos] = n;
  }
}

__global__ void k_scatter(const int* src, const int* dst, fp ea, fp w1, fp b1, fp w2, fp b2,
                          int* cursor, int* esrc, float* gcsr) {
  int e = blockIdx.x * 256 + threadIdx.x;
  if (e >= cE) return;
  float a0 = ea[e * 4 + 0], a1 = ea[e * 4 + 1], a2 = ea[e * 4 + 2], a3 = ea[e * 4 + 3];
  float acc = b2[0];
#pragma unroll
  for (int j = 0; j < 16; j++) {
    float tv = b1[j] + a0 * w1[j] + a1 * w1[16 + j] + a2 * w1[32 + j] + a3 * w1[48 + j];
    acc += ftanh(tv) * w2[j];
  }
  float g = 1.f / (1.f + __expf(-acc));
  int p = atomicAdd(&cursor[dst[e]], 1);
  esrc[p] = src[e];
  gcsr[p] = g;
}

// ---------------- setup: counts zero + h init + weight prepack ----------------
constexpr int cWTOT = 128 * 160 + 64 * 128 + 64 * 64 + 3 * 64 * 64;  // 45056
__global__ void k_setup(int* counts, float* h, u16* h_bf, fp h0, fp W_tau, fp W_g, fp W_enc,
                        fp W_lt, fp W_hop, u16* Wtg, u16* Wenc, u16* Wlt, u16* Whop) {
  int i = blockIdx.x * 256 + threadIdx.x;
  if (i < cN) counts[i] = 0;
  if (i < cBNH) {
    float v = h0[i & 63];
    h[i] = v;
    h_bf[i] = f2b(v);
  }
  if (i < 128 * 160) {
    int col = i / 160, k = i - col * 160;
    float v = 0.f;
    if (k < 133) v = (col < 64) ? W_tau[k * 64 + col] : W_g[k * 64 + (col - 64)];
    Wtg[i] = f2b(v);
  } else if (i < 128 * 160 + 64 * 128) {
    int i2 = i - 128 * 160;
    int col = i2 / 128, k = i2 - col * 128;
    Wenc[i2] = f2b(W_enc[k * 64 + col]);
  } else if (i < 128 * 160 + 64 * 128 + 64 * 64) {
    int i3 = i - 128 * 160 - 64 * 128;
    int col = i3 / 64, k = i3 - col * 64;
    Wlt[i3] = f2b(W_lt[k * 64 + col]);
  } else if (i < cWTOT) {
    int i4 = i - 128 * 160 - 64 * 128 - 64 * 64;
    int hop = i4 / 4096, rem = i4 - hop * 4096;
    int col = rem / 64, k = rem - col * 64;
    Whop[i4] = f2b(W_hop[hop * 4096 + k * 64 + col]);
  }
}

// ---------------- hop matvec: MFMA, bf16 in/out (used once, t=0 hop0) ----------------
__global__ __launch_bounds__(256) void k_hop_mat_m(const u16* vin_bf, const u16* Wh, fp avs,
                                                   fp avd, u16* hw_bf, float* ssrc,
                                                   float* sdst) {
  __shared__ u16 tin[64 * 72];
  __shared__ u16 thw[64 * 72];
  __shared__ float red1[4][64], red2[4][64];
  int tid = threadIdx.x, w = tid >> 6, lane = tid & 63;
  int quad = lane >> 4, l15 = lane & 15;
  int base = blockIdx.x * 64;
  {
    int tn = tid >> 2, cs = (tid & 3) * 16;
    int gn = base + tn;
    if (gn >= cBN) gn = cBN - 1;
    const short8* src = (const short8*)(vin_bf + (size_t)gn * 64 + cs);
    *(short8*)(tin + tn * 72 + cs) = src[0];
    *(short8*)(tin + tn * 72 + cs + 8) = src[1];
  }
  __syncthreads();
  f32x4 acc[4];
#pragma unroll
  for (int mt = 0; mt < 4; mt++) acc[mt] = (f32x4){0.f, 0.f, 0.f, 0.f};
#pragma unroll
  for (int ks = 0; ks < 2; ks++) {
    short8 bfr = *(const short8*)(Wh + (16 * w + l15) * 64 + ks * 32 + quad * 8);
#pragma unroll
    for (int mt = 0; mt < 4; mt++) {
      short8 afr = *(const short8*)(tin + (mt * 16 + l15) * 72 + ks * 32 + quad * 8);
      acc[mt] = __builtin_amdgcn_mfma_f32_16x16x32_bf16(afr, bfr, acc[mt], 0, 0, 0);
    }
  }
  int col = 16 * w + l15;
#pragma unroll
  for (int mt = 0; mt < 4; mt++) {
#pragma unroll
    for (int r = 0; r < 4; r++) {
      thw[(mt * 16 + quad * 4 + r) * 72 + col] = f2b(acc[mt][r]);
    }
  }
  __syncthreads();
  {
    float r1 = 0.f, r2 = 0.f;
#pragma unroll
    for (int c = 0; c < 16; c++) {
      float v = b2f(thw[lane * 72 + 16 * w + c]);
      r1 += v * avs[16 * w + c];
      r2 += v * avd[16 * w + c];
    }
    red1[w][lane] = r1;
    red2[w][lane] = r2;
  }
  __syncthreads();
  if (w == 0 && base + lane < cBN) {
    ssrc[base + lane] = red1[0][lane] + red1[1][lane] + red1[2][lane] + red1[3][lane];
    sdst[base + lane] = red2[0][lane] + red2[1][lane] + red2[2][lane] + red2[3][lane];
  }
  {
    int tn = tid >> 2, cs = (tid & 3) * 16;
    int gn = base + tn;
    if (gn < cBN) {
      short8* dst = (short8*)(hw_bf + (size_t)gn * 64 + cs);
      dst[0] = *(const short8*)(thw + tn * 72 + cs);
      dst[1] = *(const short8*)(thw + tn * 72 + cs + 8);
    }
  }
}

// ---------------- quarter-wave hop aggregate (+ larval in HOP0, + fused matvec) --------
// Each 16-lane quarter owns one (b,n) pair: lanes load its 16 edges at once, then
// serially broadcast each edge (shfl) while all 16 lanes gather that edge's 128B row.
// Lane-private col accumulators -> no cross-lane num reduction. 16 pairs per block
// feed a full 16-row MFMA for the fused next-hop matvec.
template <int HOP>
__global__ __launch_bounds__(256) void k_hop_agg(
    const u16* hw_bf, const float* ssrc, const float* sdst, const int* row_ptr,
    const int* esrc, const float* gcsr, const u16* h_bf, float* khsum, u16* agg_bf,
    const int* perm, const u16* Wnext, fp avs_n, fp avd_n, u16* hw_out, float* ssrc_out,
    float* sdst_out) {
  __shared__ u16 cur16[16 * 72];  // bf16 A-tile for fused matvec (16 rows = 16 pairs)
  __shared__ u16 thw[16 * 64];    // fused matvec output rows
  int wv = threadIdx.x >> 6, lane = threadIdx.x & 63;
  int q = lane >> 4, ql = lane & 15, qb = q << 4;
  int p = wv * 4 + q;             // pair slot in block [0,16)
  int i = blockIdx.x * 16 + p;    // global pair id [0,20000)
  int n = perm[i >> 1];
  int b = i & 1;
  int u = b * cN + n;
  int r0 = row_ptr[n];
  int deg = row_ptr[n + 1] - r0;
  const float* sb = ssrc + (size_t)b * cN;
  float sd = sdst[u];
  // wave-uniform max degree over the 4 quarters (sorted perm -> nearly equal)
  int dmax = max(deg, __shfl_xor(deg, 16, 64));
  dmax = max(dmax, __shfl_xor(dmax, 32, 64));
  float den = 0.f;
  float num0 = 0.f, num1 = 0.f, num2 = 0.f, num3 = 0.f;
  float la0 = 0.f, la1 = 0.f, la2 = 0.f, la3 = 0.f;
  const u16* hwb = hw_bf + (size_t)b * cN * 64;
  const u16* hb = h_bf + (size_t)b * cN * 64;
  for (int j0 = 0; j0 < dmax; j0 += 16) {
    int jq = j0 + ql;
    bool v = jq < deg;
    int s = 0;
    float a = 0.f, g = 0.f;
    if (v) {
      int e = r0 + jq;
      s = esrc[e];
      if constexpr (HOP == 0) g = gcsr[e];
      float ev = sb[s] + sd;
      ev = ev > 0.f ? ev : 0.2f * ev;
      a = __expf(ev);  // |ev| small; softmax shift-invariant
    }
    den += a;
    int cnt = min(16, dmax - j0);
    for (int j = 0; j < cnt; j += 4) {
      // 4 serial edges per quarter (a=0 pads tails); 4-8 loads in flight
      int s1 = __shfl(s, qb + j, 64);     float a1 = __shfl(a, qb + j, 64);
      int s2 = __shfl(s, qb + j + 1, 64); float a2 = __shfl(a, qb + j + 1, 64);
      int s3 = __shfl(s, qb + j + 2, 64); float a3 = __shfl(a, qb + j + 2, 64);
      int s4 = __shfl(s, qb + j + 3, 64); float a4 = __shfl(a, qb + j + 3, 64);
      uint2 d1 = *(const uint2*)(hwb + (size_t)s1 * 64 + ql * 4);
      uint2 d2 = *(const uint2*)(hwb + (size_t)s2 * 64 + ql * 4);
      uint2 d3 = *(const uint2*)(hwb + (size_t)s3 * 64 + ql * 4);
      uint2 d4 = *(const uint2*)(hwb + (size_t)s4 * 64 + ql * 4);
      num0 += a1 * bl(d1.x); num1 += a1 * bh(d1.x); num2 += a1 * bl(d1.y); num3 += a1 * bh(d1.y);
      num0 += a2 * bl(d2.x); num1 += a2 * bh(d2.x); num2 += a2 * bl(d2.y); num3 += a2 * bh(d2.y);
      num0 += a3 * bl(d3.x); num1 += a3 * bh(d3.x); num2 += a3 * bl(d3.y); num3 += a3 * bh(d3.y);
      num0 += a4 * bl(d4.x); num1 += a4 * bh(d4.x); num2 += a4 * bl(d4.y); num3 += a4 * bh(d4.y);
      if constexpr (HOP == 0) {
        float g1 = __shfl(g, qb + j, 64);
        float g2 = __shfl(g, qb + j + 1, 64);
        float g3 = __shfl(g, qb + j + 2, 64);
        float g4 = __shfl(g, qb + j + 3, 64);
        uint2 e1 = *(const uint2*)(hb + (size_t)s1 * 64 + ql * 4);
        uint2 e2 = *(const uint2*)(hb + (size_t)s2 * 64 + ql * 4);
        uint2 e3 = *(const uint2*)(hb + (size_t)s3 * 64 + ql * 4);
        uint2 e4 = *(const uint2*)(hb + (size_t)s4 * 64 + ql * 4);
        la0 += g1 * bl(e1.x); la1 += g1 * bh(e1.x); la2 += g1 * bl(e1.y); la3 += g1 * bh(e1.y);
        la0 += g2 * bl(e2.x); la1 += g2 * bh(e2.x); la2 += g2 * bl(e2.y); la3 += g2 * bh(e2.y);
        la0 += g3 * bl(e3.x); la1 += g3 * bh(e3.x); la2 += g3 * bl(e3.y); la3 += g3 * bh(e3.y);
        la0 += g4 * bl(e4.x); la1 += g4 * bh(e4.x); la2 += g4 * bl(e4.y); la3 += g4 * bh(e4.y);
      }
    }
  }
  // quarter-local den reduction
  den += __shfl_xor(den, 1, 64);
  den += __shfl_xor(den, 2, 64);
  den += __shfl_xor(den, 4, 64);
  den += __shfl_xor(den, 8, 64);
  float inv = 1.f / (den + 1e-16f);
  float c0 = num0 * inv, c1 = num1 * inv, c2 = num2 * inv, c3 = num3 * inv;
  size_t ni = (size_t)u * 64 + ql * 4;
  if constexpr (HOP < 2) {
    uint2 pk;
    pk.x = ((unsigned)f2b(c1) << 16) | (unsigned)f2b(c0);
    pk.y = ((unsigned)f2b(c3) << 16) | (unsigned)f2b(c2);
    *(uint2*)(cur16 + p * 72 + ql * 4) = pk;  // LDS A-tile row p
  }
  float4* kp = (float4*)(khsum + ni);
  if constexpr (HOP == 0) {
    float4 kv;
    kv.x = c0; kv.y = c1; kv.z = c2; kv.w = c3;
    *kp = kv;
    uint2 ga;
    ga.x = ((unsigned)f2b(la1) << 16) | (unsigned)f2b(la0);
    ga.y = ((unsigned)f2b(la3) << 16) | (unsigned)f2b(la2);
    *(uint2*)(agg_bf + ni) = ga;
  } else {
    float4 kv = *kp;
    kv.x += c0; kv.y += c1; kv.z += c2; kv.w += c3;
    *kp = kv;
  }
  // ---- fused next-hop matvec: hw_out = cur @ Wnext (full 16-row MFMA) ----
  if constexpr (HOP < 2) {
    __syncthreads();
    f32x4 hacc = (f32x4){0.f, 0.f, 0.f, 0.f};
#pragma unroll
    for (int ks = 0; ks < 2; ks++) {
      short8 bfr = *(const short8*)(Wnext + (16 * wv + ql) * 64 + ks * 32 + q * 8);
      short8 afr = *(const short8*)(cur16 + ql * 72 + ks * 32 + q * 8);
      hacc = __builtin_amdgcn_mfma_f32_16x16x32_bf16(afr, bfr, hacc, 0, 0, 0);
    }
    int col = 16 * wv + ql;
#pragma unroll
    for (int r = 0; r < 4; r++) thw[(q * 4 + r) * 64 + col] = f2b(hacc[r]);
    __syncthreads();
    // write this pair's hw row (lane covers cols ql*4..+3)
    *(uint2*)(hw_out + (size_t)u * 64 + ql * 4) = *(const uint2*)(thw + p * 64 + ql * 4);
    // ssrc/sdst for the next hop: wave reduces its own 4 pairs serially
#pragma unroll
    for (int pp = 0; pp < 4; pp++) {
      float v = b2f(thw[(wv * 4 + pp) * 64 + lane]);
      float r1 = wsum(v * avs_n[lane]);
      float r2 = wsum(v * avd_n[lane]);
      int u_pp = __shfl(u, pp << 4, 64);
      if (lane == 0) {
        ssrc_out[u_pp] = r1;
        sdst_out[u_pp] = r2;
      }
    }
  }
}

// ---------------- MFMA mega-kernel: p-GEMM + tau/g GEMM + u GEMM + cell + next hop0 mat --
__global__ __launch_bounds__(256) void k_mega(fp x, int t, float* h_nm, u16* h_bf,
                                              const float* khsum, const u16* agg_bf,
                                              const int* row_ptr, const u16* Wtg,
                                              const u16* Wenc, const u16* Wlt, const u16* Whop0,
                                              fp avs0, fp avd0, u16* hw_bf, float* ssrc,
                                              float* sdst, fp b_tau, fp b_g, fp b_enc, fp gamma,
                                              fp beta, fp c_enc, fp cdec, fp W_dec, fp b_dec,
                                              float* out) {
  __shared__ __align__(16) char lds[59904];
  u16* tz = (u16*)lds;                  // [64][168] bf16
  u16* tphi = (u16*)(lds + 30720);      // [64][136] bf16
  float* tgu = (float*)lds;             // [64][197] fp32 overlay (after GEMMs)
  u16* tzh = (u16*)lds;                 // [64][72] bf16 (tail overlay)
  u16* thw2 = (u16*)(lds + 10240);      // [64][72] bf16 (tail overlay)
  float* sx = (float*)(lds + 50432);
  float* redm = (float*)(lds + 54784);  // [4][64]
  float* redv = redm + 256;             // [4][64]
  float* redp = redv + 256;             // [4][3][64]
  int tid = threadIdx.x;
  int w = tid >> 6, lane = tid & 63;
  int quad = lane >> 4, l15 = lane & 15;
  int base = blockIdx.x * 64;
  {
    int tn = tid >> 2, f4 = (tid & 3) * 4;
    int gn = base + tn;
    if (gn >= cBN) gn = cBN - 1;
    int gb = gn / cN, gnn = gn - gb * cN;
    float4 xv = *(const float4*)(x + (((size_t)gb * cT + t) * cN + gnn) * cF + f4);
    sx[tn * 17 + f4 + 0] = xv.x;
    sx[tn * 17 + f4 + 1] = xv.y;
    sx[tn * 17 + f4 + 2] = xv.z;
    sx[tn * 17 + f4 + 3] = xv.w;
    int f0 = (tid & 3) * 16;
    const short8* hs = (const short8*)(h_bf + (size_t)gn * 64 + f0);
    *(short8*)(tz + tn * 168 + f0) = hs[0];
    *(short8*)(tz + tn * 168 + f0 + 8) = hs[1];
  }
  for (int i = tid; i < 64 * 27; i += 256) {
    int nn2 = i / 27;
    tz[nn2 * 168 + 133 + (i - nn2 * 27)] = 0;
  }
  __syncthreads();
  for (int i = tid; i < 320; i += 256) {
    int j = i >> 6, n2 = i & 63;
    tz[n2 * 168 + 64 + j] = f2b(sx[n2 * 17 + 8 + j]);
  }
  // phi via RBF recurrence: per (node,f) bundle, 2 exps for 8 bases
  {
    float ec0 = c_enc[0], ec7 = c_enc[7];
    float inv_e = 7.f / (ec7 - ec0);
    for (int i = tid; i < 64 * 16; i += 256) {
      int n2 = i >> 4, f = i & 15;
      float d0 = (sx[n2 * 17 + f] - ec0) * inv_e;
      float phi = __expf(-d0 * d0);
      float r = __expf(2.f * d0 - 1.f);
      u16* dst = tphi + n2 * 136 + f * 8;
#pragma unroll
      for (int cb = 0; cb < 8; cb++) {
        dst[cb] = f2b(phi);
        phi *= r;
        r *= cEXPM2;
      }
    }
  }
  __syncthreads();
  // G2: u = phi @ Wenc
  f32x4 accU[4];
#pragma unroll
  for (int mt = 0; mt < 4; mt++) accU[mt] = (f32x4){0.f, 0.f, 0.f, 0.f};
#pragma unroll
  for (int ks = 0; ks < 4; ks++) {
    short8 bfr = *(const short8*)(Wenc + (16 * w + l15) * 128 + ks * 32 + quad * 8);
#pragma unroll
    for (int mt = 0; mt < 4; mt++) {
      short8 afr = *(const short8*)(tphi + (mt * 16 + l15) * 136 + ks * 32 + quad * 8);
      accU[mt] = __builtin_amdgcn_mfma_f32_16x16x32_bf16(afr, bfr, accU[mt], 0, 0, 0);
    }
  }
  // G0: plt = agg @ Wlt -> p rows into tz
  {
    f32x4 accP[4];
#pragma unroll
    for (int mt = 0; mt < 4; mt++) accP[mt] = (f32x4){0.f, 0.f, 0.f, 0.f};
#pragma unroll
    for (int ks = 0; ks < 2; ks++) {
      short8 bfr = *(const short8*)(Wlt + (16 * w + l15) * 64 + ks * 32 + quad * 8);
#pragma unroll
      for (int mt = 0; mt < 4; mt++) {
        int gn = base + mt * 16 + l15;
        if (gn >= cBN) gn = cBN - 1;
        short8 afr = *(const short8*)(agg_bf + (size_t)gn * 64 + ks * 32 + quad * 8);
        accP[mt] = __builtin_amdgcn_mfma_f32_16x16x32_bf16(afr, bfr, accP[mt], 0, 0, 0);
      }
    }
    int colP = 16 * w + l15;
#pragma unroll
    for (int mt = 0; mt < 4; mt++) {
#pragma unroll
      for (int r = 0; r < 4; r++) {
        int nl = mt * 16 + quad * 4 + r;
        int gn = base + nl;
        int gnc = gn < cBN ? gn : cBN - 1;
        int bB = gnc / cN, nn = gnc - bB * cN;
        float deg = (float)(row_ptr[nn + 1] - row_ptr[nn]);
        float pv = khsum[(size_t)gnc * 64 + colP] * (1.f / 3.f) + accP[mt][r] / (deg + 1.f);
        tz[nl * 168 + 69 + colP] = f2b(pv);
      }
    }
  }
  __syncthreads();
  // G1: [tau|g] = z @ Wtg (K=160)
  f32x4 accT[8];
#pragma unroll
  for (int i = 0; i < 8; i++) accT[i] = (f32x4){0.f, 0.f, 0.f, 0.f};
#pragma unroll
  for (int ks = 0; ks < 5; ks++) {
    short8 b0 = *(const short8*)(Wtg + (32 * w + l15) * 160 + ks * 32 + quad * 8);
    short8 b1 = *(const short8*)(Wtg + (32 * w + 16 + l15) * 160 + ks * 32 + quad * 8);
#pragma unroll
    for (int mt = 0; mt < 4; mt++) {
      short8 afr = *(const short8*)(tz + (mt * 16 + l15) * 168 + ks * 32 + quad * 8);
      accT[mt * 2 + 0] =
          __builtin_amdgcn_mfma_f32_16x16x32_bf16(afr, b0, accT[mt * 2 + 0], 0, 0, 0);
      accT[mt * 2 + 1] =
          __builtin_amdgcn_mfma_f32_16x16x32_bf16(afr, b1, accT[mt * 2 + 1], 0, 0, 0);
    }
  }
  __syncthreads();  // tz dead; tgu overlay
#pragma unroll
  for (int mt = 0; mt < 4; mt++) {
#pragma unroll
    for (int ntl = 0; ntl < 2; ntl++) {
#pragma unroll
      for (int r = 0; r < 4; r++) {
        int nl = mt * 16 + quad * 4 + r;
        tgu[nl * 197 + 32 * w + ntl * 16 + l15] = accT[mt * 2 + ntl][r];
      }
    }
#pragma unroll
    for (int r = 0; r < 4; r++) {
      int nl = mt * 16 + quad * 4 + r;
      tgu[nl * 197 + 128 + 16 * w + l15] = accU[mt][r];
    }
  }
  __syncthreads();
  // epilogue: thread = node lane, col chunk c0
  int c0 = __builtin_amdgcn_readfirstlane(w * 16);
  int node = base + lane;
  int ngc = node < cBN ? node : cBN - 1;
  int bb = ngc / cN, nn = ngc - bb * cN;
  float hv[16];
  {
    const float4* hp = (const float4*)(h_nm + (size_t)ngc * 64 + c0);
#pragma unroll
    for (int q = 0; q < 4; q++) {
      float4 v = hp[q];
      hv[q * 4 + 0] = v.x; hv[q * 4 + 1] = v.y; hv[q * 4 + 2] = v.z; hv[q * 4 + 3] = v.w;
    }
  }
  float acc[16];
  float pm = 0.f;
#pragma unroll
  for (int c = 0; c < 16; c++) {
    float at = tgu[lane * 197 + c0 + c] + b_tau[c0 + c];
    float ag = tgu[lane * 197 + 64 + c0 + c] + b_g[c0 + c];
    float tau = 1.f + 9.f / (1.f + __expf(-at));
    float g = ftanh(ag);
    float v = hv[c] + 0.25f * (g - hv[c]) / tau;
    acc[c] = v;
    pm += v;
  }
  redm[w * 64 + lane] = pm;
  __syncthreads();
  float mu = (redm[lane] + redm[64 + lane] + redm[128 + lane] + redm[192 + lane]) * (1.f / 64.f);
  float pv = 0.f;
#pragma unroll
  for (int c = 0; c < 16; c++) {
    float d = acc[c] - mu;
    pv += d * d;
  }
  redv[w * 64 + lane] = pv;
  __syncthreads();
  float var = (redv[lane] + redv[64 + lane] + redv[128 + lane] + redv[192 + lane]) * (1.f / 64.f);
  float rstd = rsqrtf(var + 1e-5f);
#pragma unroll
  for (int c = 0; c < 16; c++) {
    acc[c] = (acc[c] - mu) * rstd * gamma[c0 + c] + beta[c0 + c] +
             tgu[lane * 197 + 128 + c0 + c] + b_enc[c0 + c];
  }
  if (node < cBN) {
    float4* hp = (float4*)(h_nm + (size_t)ngc * 64 + c0);
#pragma unroll
    for (int q = 0; q < 4; q++) {
      float4 v;
      v.x = acc[q * 4 + 0]; v.y = acc[q * 4 + 1]; v.z = acc[q * 4 + 2]; v.w = acc[q * 4 + 3];
      hp[q] = v;
    }
    unsigned* bp = (unsigned*)(h_bf + (size_t)ngc * 64 + c0);
#pragma unroll
    for (int q = 0; q < 8; q++) {
      unsigned lo = f2b(acc[q * 2 + 0]);
      unsigned hi = f2b(acc[q * 2 + 1]);
      bp[q] = (hi << 16) | lo;
    }
  }
  // decoder fastkan (RBF recurrence: 2 exps per col) + softplus
  float dc0 = cdec[0], dc7 = cdec[7];
  float inv_d = 7.f / (dc7 - dc0);
  float p0 = 0.f, p1 = 0.f, p2 = 0.f;
#pragma unroll
  for (int c = 0; c < 16; c++) {
    float d0 = (acc[c] - dc0) * inv_d;
    float ph = __expf(-d0 * d0);
    float r = __expf(2.f * d0 - 1.f);
    const float* Wd = W_dec + (c0 + c) * 24;
#pragma unroll
    for (int j = 0; j < 8; j++) {
      p0 += ph * Wd[j * 3];
      p1 += ph * Wd[j * 3 + 1];
      p2 += ph * Wd[j * 3 + 2];
      ph *= r;
      r *= cEXPM2;
    }
  }
  redp[(w * 3 + 0) * 64 + lane] = p0;
  redp[(w * 3 + 1) * 64 + lane] = p1;
  redp[(w * 3 + 2) * 64 + lane] = p2;
  __syncthreads();  // also: all tgu reads complete -> tail overlay safe
  if (w == 0 && node < cBN) {
    float v0 = redp[0 * 64 + lane] + redp[3 * 64 + lane] + redp[6 * 64 + lane] +
               redp[9 * 64 + lane] + b_dec[0];
    float v1 = redp[1 * 64 + lane] + redp[4 * 64 + lane] + redp[7 * 64 + lane] +
               redp[10 * 64 + lane] + b_dec[1];
    float v2 = redp[2 * 64 + lane] + redp[5 * 64 + lane] + redp[8 * 64 + lane] +
               redp[11 * 64 + lane] + b_dec[2];
    size_t ob = (((size_t)bb * cT + t) * cN + nn) * 3;
    out[ob] = fmaxf(v0, 0.f) + log1pf(__expf(-fabsf(v0)));
    out[ob + 1] = fmaxf(v1, 0.f) + log1pf(__expf(-fabsf(v1)));
    out[ob + 2] = fmaxf(v2, 0.f) + log1pf(__expf(-fabsf(v2)));
  }
  // ---- fused tail: next-step hop0 matvec (node-local: uses just-computed h) ----
#pragma unroll
  for (int c = 0; c < 16; c++) tzh[lane * 72 + c0 + c] = f2b(acc[c]);
  __syncthreads();
  f32x4 hacc[4];
#pragma unroll
  for (int mt = 0; mt < 4; mt++) hacc[mt] = (f32x4){0.f, 0.f, 0.f, 0.f};
#pragma unroll
  for (int ks = 0; ks < 2; ks++) {
    short8 bfr = *(const short8*)(Whop0 + (16 * w + l15) * 64 + ks * 32 + quad * 8);
#pragma unroll
    for (int mt = 0; mt < 4; mt++) {
      short8 afr = *(const short8*)(tzh + (mt * 16 + l15) * 72 + ks * 32 + quad * 8);
      hacc[mt] = __builtin_amdgcn_mfma_f32_16x16x32_bf16(afr, bfr, hacc[mt], 0, 0, 0);
    }
  }
  int colh = 16 * w + l15;
#pragma unroll
  for (int mt = 0; mt < 4; mt++) {
#pragma unroll
    for (int r = 0; r < 4; r++) {
      thw2[(mt * 16 + quad * 4 + r) * 72 + colh] = f2b(hacc[mt][r]);
    }
  }
  __syncthreads();
  {
    float r1 = 0.f, r2 = 0.f;
#pragma unroll
    for (int c = 0; c < 16; c++) {
      float v = b2f(thw2[lane * 72 + 16 * w + c]);
      r1 += v * avs0[16 * w + c];
      r2 += v * avd0[16 * w + c];
    }
    redm[w * 64 + lane] = r1;
    redv[w * 64 + lane] = r2;
  }
  __syncthreads();
  if (w == 0 && node < cBN) {
    ssrc[node] = redm[lane] + redm[64 + lane] + redm[128 + lane] + redm[192 + lane];
    sdst[node] = redv[lane] + redv[64 + lane] + redv[128 + lane] + redv[192 + lane];
  }
  {
    int tn = tid >> 2, cs = (tid & 3) * 16;
    int gn = base + tn;
    if (gn < cBN) {
      short8* dst = (short8*)(hw_bf + (size_t)gn * 64 + cs);
      dst[0] = *(const short8*)(thw2 + tn * 72 + cs);
      dst[1] = *(const short8*)(thw2 + tn * 72 + cs + 8);
    }
  }
}

extern "C" void kernel_launch(void* const* d_in, const int* in_sizes, int n_in, void* d_out,
                              int out_size, void* d_ws, size_t ws_size, hipStream_t stream) {
  fp x = (fp)d_in[0];
  fp edge_attr = (fp)d_in[1];
  fp c_enc = (fp)d_in[2];
  fp W_enc = (fp)d_in[3];
  fp b_enc = (fp)d_in[4];
  fp W_hop = (fp)d_in[5];
  fp a_src = (fp)d_in[6];
  fp a_dst = (fp)d_in[7];
  fp w_lt1 = (fp)d_in[8];
  fp b_lt1 = (fp)d_in[9];
  fp w_lt2 = (fp)d_in[10];
  fp b_lt2 = (fp)d_in[11];
  fp W_lt = (fp)d_in[12];
  fp W_tau = (fp)d_in[13];
  fp b_tau = (fp)d_in[14];
  fp W_g = (fp)d_in[15];
  fp b_g = (fp)d_in[16];
  fp gamma = (fp)d_in[17];
  fp beta = (fp)d_in[18];
  fp c_dec = (fp)d_in[19];
  fp W_dec = (fp)d_in[20];
  fp b_dec = (fp)d_in[21];
  fp h0 = (fp)d_in[22];
  const int* eidx = (const int*)d_in[23];
  const int* esrc_in = eidx;
  const int* edst_in = eidx + cE;

  float* fws = (float*)d_ws;
  float* h_nm = fws;   fws += cBNH;
  float* khsum = fws;  fws += cBNH;
  float* ssrc = fws;   fws += cBN;
  float* sdst = fws;   fws += cBN;
  float* ssrc2 = fws;  fws += cBN;
  float* sdst2 = fws;  fws += cBN;
  float* gcsr = fws;   fws += cE;
  u16* h_bf = (u16*)fws;    fws += cBNH / 2;
  u16* hw_bf = (u16*)fws;   fws += cBNH / 2;
  u16* hw_bf2 = (u16*)fws;  fws += cBNH / 2;
  u16* agg_bf = (u16*)fws;  fws += cBNH / 2;
  u16* Wtg = (u16*)fws;   fws += (128 * 160) / 2;
  u16* Wenc = (u16*)fws;  fws += (64 * 128) / 2;
  u16* Wlt = (u16*)fws;   fws += (64 * 64) / 2;
  u16* Whop = (u16*)fws;  fws += (3 * 64 * 64) / 2;
  int* iws = (int*)fws;
  int* esrc = iws;    iws += cE;
  int* row_ptr = iws; iws += cN + 1;
  int* cursor = iws;  iws += cN;
  int* counts = iws;  iws += cN;
  int* perm = iws;    iws += cN;

  k_setup<<<(cBNH + 255) / 256, 256, 0, stream>>>(counts, h_nm, h_bf, h0, W_tau, W_g, W_enc,
                                                  W_lt, W_hop, Wtg, Wenc, Wlt, Whop);
  k_count<<<(cE + 255) / 256, 256, 0, stream>>>(edst_in, counts);
  k_scan<<<1, 1024, 0, stream>>>(counts, row_ptr, cursor);
  k_dsort<<<1, 1024, 0, stream>>>(counts, perm);
  k_scatter<<<(cE + 255) / 256, 256, 0, stream>>>(esrc_in, edst_in, edge_attr, w_lt1, b_lt1,
                                                  w_lt2, b_lt2, cursor, esrc, gcsr);
  // initial hop0 matvec for t=0 (later steps get it fused into k_mega's tail)
  k_hop_mat_m<<<NBLK, 256, 0, stream>>>(h_bf, Whop, a_src, a_dst, hw_bf, ssrc, sdst);

  for (int t = 0; t < cT; t++) {
    // hop0 (+larval): read set0, fused mat writes set1
    k_hop_agg<0><<<ABLK, 256, 0, stream>>>(hw_bf, ssrc, sdst, row_ptr, esrc, gcsr, h_bf,
                                           khsum, agg_bf, perm, Whop + 4096, a_src + cH,
                                           a_dst + cH, hw_bf2, ssrc2, sdst2);
    // hop1: read set1, fused mat writes set0
    k_hop_agg<1><<<ABLK, 256, 0, stream>>>(hw_bf2, ssrc2, sdst2, row_ptr, esrc, gcsr, h_bf,
                                           khsum, agg_bf, perm, Whop + 2 * 4096,
                                           a_src + 2 * cH, a_dst + 2 * cH, hw_bf, ssrc, sdst);
    // hop2: read set0, no fused mat
    k_hop_agg<2><<<ABLK, 256, 0, stream>>>(hw_bf, ssrc, sdst, row_ptr, esrc, gcsr, h_bf,
                                           khsum, agg_bf, perm, nullptr, nullptr, nullptr,
                                           nullptr, nullptr, nullptr);
    k_mega<<<NBLK, 256, 0, stream>>>(x, t, h_nm, h_bf, khsum, agg_bf, row_ptr, Wtg, Wenc, Wlt,
                                     Whop, a_src, a_dst, hw_bf, ssrc, sdst, b_tau, b_g, b_enc,
                                     gamma, beta, c_enc, c_dec, W_dec, b_dec, (float*)d_out);
  }
}

// Round 7
// 292.896 us; speedup vs baseline: 1.3056x; 1.0470x over previous
//
#include <hip/hip_runtime.h>
#include <hip/hip_bf16.h>
#include <math.h>

// SeaLiceGLKAN — fp32 in/out. R21: R20 quarter-wave gather + (a) quarter-
// parallel ssrc/sdst tail (8 shfls/wave instead of 48 + serial LDS), (b)
// 8-deep gather unroll for hops 1/2 (2x outstanding loads). hop0 stays
// 4-deep (larval rows already double its loads in flight).

constexpr int cB = 2, cT = 4, cN = 10000, cF = 16, cH = 64, cE = 160000, cK = 3;
constexpr int cBN = cB * cN;    // 20000
constexpr int cBNH = cBN * cH;  // 1,280,000
constexpr int NBLK = (cBN + 63) / 64;   // 313 nodegroups of 64
constexpr int ABLK = cBN / 16;          // 1250 agg blocks (16 pairs each)

typedef const float* fp;
typedef short short8 __attribute__((ext_vector_type(8)));
typedef float f32x4 __attribute__((ext_vector_type(4)));
typedef unsigned short u16;

constexpr float cEXPM2 = 0.13533528323661270f;  // exp(-2)

__device__ __forceinline__ float wsum(float v) {
#pragma unroll
  for (int o = 1; o < 64; o <<= 1) v += __shfl_xor(v, o, 64);
  return v;
}
__device__ __forceinline__ u16 f2b(float f) {  // fp32 -> bf16 bits (RNE)
  unsigned u = __float_as_uint(f);
  u += 0x7FFFu + ((u >> 16) & 1u);
  return (u16)(u >> 16);
}
__device__ __forceinline__ float b2f(u16 b) { return __uint_as_float(((unsigned)b) << 16); }
__device__ __forceinline__ float bl(unsigned x) { return __uint_as_float(x << 16); }
__device__ __forceinline__ float bh(unsigned x) { return __uint_as_float(x & 0xffff0000u); }
__device__ __forceinline__ float ftanh(float x) {
  float e = __expf(2.f * x);
  return (e - 1.f) / (e + 1.f);
}

// ---------------- CSR build ----------------
__global__ void k_count(const int* dst, int* counts) {
  int e = blockIdx.x * 256 + threadIdx.x;
  if (e < cE) atomicAdd(&counts[dst[e]], 1);
}

__global__ void k_scan(const int* counts, int* row_ptr, int* cursor) {
  __shared__ int part[1024];
  int t = threadIdx.x;
  const int CH = (cN + 1023) / 1024;  // 10
  int s = 0;
  for (int i = 0; i < CH; i++) {
    int idx = t * CH + i;
    if (idx < cN) s += counts[idx];
  }
  part[t] = s;
  __syncthreads();
  for (int off = 1; off < 1024; off <<= 1) {
    int v = (t >= off) ? part[t - off] : 0;
    __syncthreads();
    part[t] += v;
    __syncthreads();
  }
  int excl = (t == 0) ? 0 : part[t - 1];
  for (int i = 0; i < CH; i++) {
    int idx = t * CH + i;
    if (idx < cN) {
      row_ptr[idx] = excl;
      cursor[idx] = excl;
      excl += counts[idx];
    }
  }
  if (t == 1023) row_ptr[cN] = part[1023];
}

// descending-degree counting sort: perm[pos] = node, heaviest first.
__global__ void k_dsort(const int* counts, int* perm) {
  __shared__ int bins[64], boff[64];
  int t = threadIdx.x;
  if (t < 64) bins[t] = 0;
  __syncthreads();
  for (int n = t; n < cN; n += 1024) {
    int d = counts[n];
    if (d > 63) d = 63;
    atomicAdd(&bins[63 - d], 1);
  }
  __syncthreads();
  if (t == 0) {
    int acc = 0;
    for (int i = 0; i < 64; i++) {
      boff[i] = acc;
      acc += bins[i];
    }
  }
  __syncthreads();
  for (int n = t; n < cN; n += 1024) {
    int d = counts[n];
    if (d > 63) d = 63;
    int pos = atomicAdd(&boff[63 - d], 1);
    perm[pos] = n;
  }
}

__global__ void k_scatter(const int* src, const int* dst, fp ea, fp w1, fp b1, fp w2, fp b2,
                          int* cursor, int* esrc, float* gcsr) {
  int e = blockIdx.x * 256 + threadIdx.x;
  if (e >= cE) return;
  float a0 = ea[e * 4 + 0], a1 = ea[e * 4 + 1], a2 = ea[e * 4 + 2], a3 = ea[e * 4 + 3];
  float acc = b2[0];
#pragma unroll
  for (int j = 0; j < 16; j++) {
    float tv = b1[j] + a0 * w1[j] + a1 * w1[16 + j] + a2 * w1[32 + j] + a3 * w1[48 + j];
    acc += ftanh(tv) * w2[j];
  }
  float g = 1.f / (1.f + __expf(-acc));
  int p = atomicAdd(&cursor[dst[e]], 1);
  esrc[p] = src[e];
  gcsr[p] = g;
}

// ---------------- setup: counts zero + h init + weight prepack ----------------
constexpr int cWTOT = 128 * 160 + 64 * 128 + 64 * 64 + 3 * 64 * 64;  // 45056
__global__ void k_setup(int* counts, float* h, u16* h_bf, fp h0, fp W_tau, fp W_g, fp W_enc,
                        fp W_lt, fp W_hop, u16* Wtg, u16* Wenc, u16* Wlt, u16* Whop) {
  int i = blockIdx.x * 256 + threadIdx.x;
  if (i < cN) counts[i] = 0;
  if (i < cBNH) {
    float v = h0[i & 63];
    h[i] = v;
    h_bf[i] = f2b(v);
  }
  if (i < 128 * 160) {
    int col = i / 160, k = i - col * 160;
    float v = 0.f;
    if (k < 133) v = (col < 64) ? W_tau[k * 64 + col] : W_g[k * 64 + (col - 64)];
    Wtg[i] = f2b(v);
  } else if (i < 128 * 160 + 64 * 128) {
    int i2 = i - 128 * 160;
    int col = i2 / 128, k = i2 - col * 128;
    Wenc[i2] = f2b(W_enc[k * 64 + col]);
  } else if (i < 128 * 160 + 64 * 128 + 64 * 64) {
    int i3 = i - 128 * 160 - 64 * 128;
    int col = i3 / 64, k = i3 - col * 64;
    Wlt[i3] = f2b(W_lt[k * 64 + col]);
  } else if (i < cWTOT) {
    int i4 = i - 128 * 160 - 64 * 128 - 64 * 64;
    int hop = i4 / 4096, rem = i4 - hop * 4096;
    int col = rem / 64, k = rem - col * 64;
    Whop[i4] = f2b(W_hop[hop * 4096 + k * 64 + col]);
  }
}

// ---------------- hop matvec: MFMA, bf16 in/out (used once, t=0 hop0) ----------------
__global__ __launch_bounds__(256) void k_hop_mat_m(const u16* vin_bf, const u16* Wh, fp avs,
                                                   fp avd, u16* hw_bf, float* ssrc,
                                                   float* sdst) {
  __shared__ u16 tin[64 * 72];
  __shared__ u16 thw[64 * 72];
  __shared__ float red1[4][64], red2[4][64];
  int tid = threadIdx.x, w = tid >> 6, lane = tid & 63;
  int quad = lane >> 4, l15 = lane & 15;
  int base = blockIdx.x * 64;
  {
    int tn = tid >> 2, cs = (tid & 3) * 16;
    int gn = base + tn;
    if (gn >= cBN) gn = cBN - 1;
    const short8* src = (const short8*)(vin_bf + (size_t)gn * 64 + cs);
    *(short8*)(tin + tn * 72 + cs) = src[0];
    *(short8*)(tin + tn * 72 + cs + 8) = src[1];
  }
  __syncthreads();
  f32x4 acc[4];
#pragma unroll
  for (int mt = 0; mt < 4; mt++) acc[mt] = (f32x4){0.f, 0.f, 0.f, 0.f};
#pragma unroll
  for (int ks = 0; ks < 2; ks++) {
    short8 bfr = *(const short8*)(Wh + (16 * w + l15) * 64 + ks * 32 + quad * 8);
#pragma unroll
    for (int mt = 0; mt < 4; mt++) {
      short8 afr = *(const short8*)(tin + (mt * 16 + l15) * 72 + ks * 32 + quad * 8);
      acc[mt] = __builtin_amdgcn_mfma_f32_16x16x32_bf16(afr, bfr, acc[mt], 0, 0, 0);
    }
  }
  int col = 16 * w + l15;
#pragma unroll
  for (int mt = 0; mt < 4; mt++) {
#pragma unroll
    for (int r = 0; r < 4; r++) {
      thw[(mt * 16 + quad * 4 + r) * 72 + col] = f2b(acc[mt][r]);
    }
  }
  __syncthreads();
  {
    float r1 = 0.f, r2 = 0.f;
#pragma unroll
    for (int c = 0; c < 16; c++) {
      float v = b2f(thw[lane * 72 + 16 * w + c]);
      r1 += v * avs[16 * w + c];
      r2 += v * avd[16 * w + c];
    }
    red1[w][lane] = r1;
    red2[w][lane] = r2;
  }
  __syncthreads();
  if (w == 0 && base + lane < cBN) {
    ssrc[base + lane] = red1[0][lane] + red1[1][lane] + red1[2][lane] + red1[3][lane];
    sdst[base + lane] = red2[0][lane] + red2[1][lane] + red2[2][lane] + red2[3][lane];
  }
  {
    int tn = tid >> 2, cs = (tid & 3) * 16;
    int gn = base + tn;
    if (gn < cBN) {
      short8* dst = (short8*)(hw_bf + (size_t)gn * 64 + cs);
      dst[0] = *(const short8*)(thw + tn * 72 + cs);
      dst[1] = *(const short8*)(thw + tn * 72 + cs + 8);
    }
  }
}

// ---------------- quarter-wave hop aggregate (+ larval in HOP0, + fused matvec) --------
// Each 16-lane quarter owns one (b,n) pair. Lane-private col accumulators; 8-deep
// unroll for hops 1/2; quarter-parallel ssrc/sdst tail (no serial wsum64 loop).
template <int HOP>
__global__ __launch_bounds__(256) void k_hop_agg(
    const u16* hw_bf, const float* ssrc, const float* sdst, const int* row_ptr,
    const int* esrc, const float* gcsr, const u16* h_bf, float* khsum, u16* agg_bf,
    const int* perm, const u16* Wnext, fp avs_n, fp avd_n, u16* hw_out, float* ssrc_out,
    float* sdst_out) {
  __shared__ u16 cur16[16 * 72];  // bf16 A-tile for fused matvec (16 rows = 16 pairs)
  __shared__ u16 thw[16 * 64];    // fused matvec output rows
  int wv = threadIdx.x >> 6, lane = threadIdx.x & 63;
  int q = lane >> 4, ql = lane & 15, qb = q << 4;
  int p = wv * 4 + q;             // pair slot in block [0,16)
  int i = blockIdx.x * 16 + p;    // global pair id [0,20000)
  int n = perm[i >> 1];
  int b = i & 1;
  int u = b * cN + n;
  int r0 = row_ptr[n];
  int deg = row_ptr[n + 1] - r0;
  const float* sb = ssrc + (size_t)b * cN;
  float sd = sdst[u];
  // wave-uniform max degree over the 4 quarters (sorted perm -> nearly equal)
  int dmax = max(deg, __shfl_xor(deg, 16, 64));
  dmax = max(dmax, __shfl_xor(dmax, 32, 64));
  float den = 0.f;
  float num0 = 0.f, num1 = 0.f, num2 = 0.f, num3 = 0.f;
  float la0 = 0.f, la1 = 0.f, la2 = 0.f, la3 = 0.f;
  const u16* hwb = hw_bf + (size_t)b * cN * 64;
  const u16* hb = h_bf + (size_t)b * cN * 64;
  constexpr int UN = (HOP == 0) ? 4 : 8;  // hop0 already has 2x loads (larval rows)
  for (int j0 = 0; j0 < dmax; j0 += 16) {
    int jq = j0 + ql;
    bool v = jq < deg;
    int s = 0;
    float a = 0.f, g = 0.f;
    if (v) {
      int e = r0 + jq;
      s = esrc[e];
      if constexpr (HOP == 0) g = gcsr[e];
      float ev = sb[s] + sd;
      ev = ev > 0.f ? ev : 0.2f * ev;
      a = __expf(ev);  // |ev| small; softmax shift-invariant
    }
    den += a;
    int cnt = min(16, dmax - j0);
    for (int j = 0; j < cnt; j += UN) {
      // UN serial edges per quarter (a=0 pads tails); UN(+UN) loads in flight
      int ss[UN];
      float aa[UN];
#pragma unroll
      for (int k = 0; k < UN; k++) {
        ss[k] = __shfl(s, qb + j + k, 64);
        aa[k] = __shfl(a, qb + j + k, 64);
      }
      uint2 dd[UN];
#pragma unroll
      for (int k = 0; k < UN; k++) {
        dd[k] = *(const uint2*)(hwb + (size_t)ss[k] * 64 + ql * 4);
      }
      if constexpr (HOP == 0) {
        float gg[UN];
        uint2 ee[UN];
#pragma unroll
        for (int k = 0; k < UN; k++) gg[k] = __shfl(g, qb + j + k, 64);
#pragma unroll
        for (int k = 0; k < UN; k++) {
          ee[k] = *(const uint2*)(hb + (size_t)ss[k] * 64 + ql * 4);
        }
#pragma unroll
        for (int k = 0; k < UN; k++) {
          num0 += aa[k] * bl(dd[k].x); num1 += aa[k] * bh(dd[k].x);
          num2 += aa[k] * bl(dd[k].y); num3 += aa[k] * bh(dd[k].y);
          la0 += gg[k] * bl(ee[k].x); la1 += gg[k] * bh(ee[k].x);
          la2 += gg[k] * bl(ee[k].y); la3 += gg[k] * bh(ee[k].y);
        }
      } else {
#pragma unroll
        for (int k = 0; k < UN; k++) {
          num0 += aa[k] * bl(dd[k].x); num1 += aa[k] * bh(dd[k].x);
          num2 += aa[k] * bl(dd[k].y); num3 += aa[k] * bh(dd[k].y);
        }
      }
    }
  }
  // quarter-local den reduction
  den += __shfl_xor(den, 1, 64);
  den += __shfl_xor(den, 2, 64);
  den += __shfl_xor(den, 4, 64);
  den += __shfl_xor(den, 8, 64);
  float inv = 1.f / (den + 1e-16f);
  float c0 = num0 * inv, c1 = num1 * inv, c2 = num2 * inv, c3 = num3 * inv;
  size_t ni = (size_t)u * 64 + ql * 4;
  if constexpr (HOP < 2) {
    uint2 pk;
    pk.x = ((unsigned)f2b(c1) << 16) | (unsigned)f2b(c0);
    pk.y = ((unsigned)f2b(c3) << 16) | (unsigned)f2b(c2);
    *(uint2*)(cur16 + p * 72 + ql * 4) = pk;  // LDS A-tile row p
  }
  float4* kp = (float4*)(khsum + ni);
  if constexpr (HOP == 0) {
    float4 kv;
    kv.x = c0; kv.y = c1; kv.z = c2; kv.w = c3;
    *kp = kv;
    uint2 ga;
    ga.x = ((unsigned)f2b(la1) << 16) | (unsigned)f2b(la0);
    ga.y = ((unsigned)f2b(la3) << 16) | (unsigned)f2b(la2);
    *(uint2*)(agg_bf + ni) = ga;
  } else {
    float4 kv = *kp;
    kv.x += c0; kv.y += c1; kv.z += c2; kv.w += c3;
    *kp = kv;
  }
  // ---- fused next-hop matvec: hw_out = cur @ Wnext (full 16-row MFMA) ----
  if constexpr (HOP < 2) {
    __syncthreads();
    f32x4 hacc = (f32x4){0.f, 0.f, 0.f, 0.f};
#pragma unroll
    for (int ks = 0; ks < 2; ks++) {
      short8 bfr = *(const short8*)(Wnext + (16 * wv + ql) * 64 + ks * 32 + q * 8);
      short8 afr = *(const short8*)(cur16 + ql * 72 + ks * 32 + q * 8);
      hacc = __builtin_amdgcn_mfma_f32_16x16x32_bf16(afr, bfr, hacc, 0, 0, 0);
    }
    int col = 16 * wv + ql;
#pragma unroll
    for (int r = 0; r < 4; r++) thw[(q * 4 + r) * 64 + col] = f2b(hacc[r]);
    __syncthreads();
    // write this pair's hw row (lane covers cols ql*4..+3)
    uint2 tv = *(const uint2*)(thw + p * 64 + ql * 4);
    *(uint2*)(hw_out + (size_t)u * 64 + ql * 4) = tv;
    // quarter-parallel ssrc/sdst: each quarter reduces its own pair (16-lane tree)
    float v0 = bl(tv.x), v1 = bh(tv.x), v2 = bl(tv.y), v3 = bh(tv.y);
    float4 as4 = *(const float4*)(avs_n + ql * 4);
    float4 ad4 = *(const float4*)(avd_n + ql * 4);
    float r1 = v0 * as4.x + v1 * as4.y + v2 * as4.z + v3 * as4.w;
    float r2 = v0 * ad4.x + v1 * ad4.y + v2 * ad4.z + v3 * ad4.w;
#pragma unroll
    for (int o = 1; o < 16; o <<= 1) {
      r1 += __shfl_xor(r1, o, 64);
      r2 += __shfl_xor(r2, o, 64);
    }
    if (ql == 0) {
      ssrc_out[u] = r1;
      sdst_out[u] = r2;
    }
  }
}

// ---------------- MFMA mega-kernel: p-GEMM + tau/g GEMM + u GEMM + cell + next hop0 mat --
__global__ __launch_bounds__(256) void k_mega(fp x, int t, float* h_nm, u16* h_bf,
                                              const float* khsum, const u16* agg_bf,
                                              const int* row_ptr, const u16* Wtg,
                                              const u16* Wenc, const u16* Wlt, const u16* Whop0,
                                              fp avs0, fp avd0, u16* hw_bf, float* ssrc,
                                              float* sdst, fp b_tau, fp b_g, fp b_enc, fp gamma,
                                              fp beta, fp c_enc, fp cdec, fp W_dec, fp b_dec,
                                              float* out) {
  __shared__ __align__(16) char lds[59904];
  u16* tz = (u16*)lds;                  // [64][168] bf16
  u16* tphi = (u16*)(lds + 30720);      // [64][136] bf16
  float* tgu = (float*)lds;             // [64][197] fp32 overlay (after GEMMs)
  u16* tzh = (u16*)lds;                 // [64][72] bf16 (tail overlay)
  u16* thw2 = (u16*)(lds + 10240);      // [64][72] bf16 (tail overlay)
  float* sx = (float*)(lds + 50432);
  float* redm = (float*)(lds + 54784);  // [4][64]
  float* redv = redm + 256;             // [4][64]
  float* redp = redv + 256;             // [4][3][64]
  int tid = threadIdx.x;
  int w = tid >> 6, lane = tid & 63;
  int quad = lane >> 4, l15 = lane & 15;
  int base = blockIdx.x * 64;
  {
    int tn = tid >> 2, f4 = (tid & 3) * 4;
    int gn = base + tn;
    if (gn >= cBN) gn = cBN - 1;
    int gb = gn / cN, gnn = gn - gb * cN;
    float4 xv = *(const float4*)(x + (((size_t)gb * cT + t) * cN + gnn) * cF + f4);
    sx[tn * 17 + f4 + 0] = xv.x;
    sx[tn * 17 + f4 + 1] = xv.y;
    sx[tn * 17 + f4 + 2] = xv.z;
    sx[tn * 17 + f4 + 3] = xv.w;
    int f0 = (tid & 3) * 16;
    const short8* hs = (const short8*)(h_bf + (size_t)gn * 64 + f0);
    *(short8*)(tz + tn * 168 + f0) = hs[0];
    *(short8*)(tz + tn * 168 + f0 + 8) = hs[1];
  }
  for (int i = tid; i < 64 * 27; i += 256) {
    int nn2 = i / 27;
    tz[nn2 * 168 + 133 + (i - nn2 * 27)] = 0;
  }
  __syncthreads();
  for (int i = tid; i < 320; i += 256) {
    int j = i >> 6, n2 = i & 63;
    tz[n2 * 168 + 64 + j] = f2b(sx[n2 * 17 + 8 + j]);
  }
  // phi via RBF recurrence: per (node,f) bundle, 2 exps for 8 bases
  {
    float ec0 = c_enc[0], ec7 = c_enc[7];
    float inv_e = 7.f / (ec7 - ec0);
    for (int i = tid; i < 64 * 16; i += 256) {
      int n2 = i >> 4, f = i & 15;
      float d0 = (sx[n2 * 17 + f] - ec0) * inv_e;
      float phi = __expf(-d0 * d0);
      float r = __expf(2.f * d0 - 1.f);
      u16* dst = tphi + n2 * 136 + f * 8;
#pragma unroll
      for (int cb = 0; cb < 8; cb++) {
        dst[cb] = f2b(phi);
        phi *= r;
        r *= cEXPM2;
      }
    }
  }
  __syncthreads();
  // G2: u = phi @ Wenc
  f32x4 accU[4];
#pragma unroll
  for (int mt = 0; mt < 4; mt++) accU[mt] = (f32x4){0.f, 0.f, 0.f, 0.f};
#pragma unroll
  for (int ks = 0; ks < 4; ks++) {
    short8 bfr = *(const short8*)(Wenc + (16 * w + l15) * 128 + ks * 32 + quad * 8);
#pragma unroll
    for (int mt = 0; mt < 4; mt++) {
      short8 afr = *(const short8*)(tphi + (mt * 16 + l15) * 136 + ks * 32 + quad * 8);
      accU[mt] = __builtin_amdgcn_mfma_f32_16x16x32_bf16(afr, bfr, accU[mt], 0, 0, 0);
    }
  }
  // G0: plt = agg @ Wlt -> p rows into tz
  {
    f32x4 accP[4];
#pragma unroll
    for (int mt = 0; mt < 4; mt++) accP[mt] = (f32x4){0.f, 0.f, 0.f, 0.f};
#pragma unroll
    for (int ks = 0; ks < 2; ks++) {
      short8 bfr = *(const short8*)(Wlt + (16 * w + l15) * 64 + ks * 32 + quad * 8);
#pragma unroll
      for (int mt = 0; mt < 4; mt++) {
        int gn = base + mt * 16 + l15;
        if (gn >= cBN) gn = cBN - 1;
        short8 afr = *(const short8*)(agg_bf + (size_t)gn * 64 + ks * 32 + quad * 8);
        accP[mt] = __builtin_amdgcn_mfma_f32_16x16x32_bf16(afr, bfr, accP[mt], 0, 0, 0);
      }
    }
    int colP = 16 * w + l15;
#pragma unroll
    for (int mt = 0; mt < 4; mt++) {
#pragma unroll
      for (int r = 0; r < 4; r++) {
        int nl = mt * 16 + quad * 4 + r;
        int gn = base + nl;
        int gnc = gn < cBN ? gn : cBN - 1;
        int bB = gnc / cN, nn = gnc - bB * cN;
        float deg = (float)(row_ptr[nn + 1] - row_ptr[nn]);
        float pv = khsum[(size_t)gnc * 64 + colP] * (1.f / 3.f) + accP[mt][r] / (deg + 1.f);
        tz[nl * 168 + 69 + colP] = f2b(pv);
      }
    }
  }
  __syncthreads();
  // G1: [tau|g] = z @ Wtg (K=160)
  f32x4 accT[8];
#pragma unroll
  for (int i = 0; i < 8; i++) accT[i] = (f32x4){0.f, 0.f, 0.f, 0.f};
#pragma unroll
  for (int ks = 0; ks < 5; ks++) {
    short8 b0 = *(const short8*)(Wtg + (32 * w + l15) * 160 + ks * 32 + quad * 8);
    short8 b1 = *(const short8*)(Wtg + (32 * w + 16 + l15) * 160 + ks * 32 + quad * 8);
#pragma unroll
    for (int mt = 0; mt < 4; mt++) {
      short8 afr = *(const short8*)(tz + (mt * 16 + l15) * 168 + ks * 32 + quad * 8);
      accT[mt * 2 + 0] =
          __builtin_amdgcn_mfma_f32_16x16x32_bf16(afr, b0, accT[mt * 2 + 0], 0, 0, 0);
      accT[mt * 2 + 1] =
          __builtin_amdgcn_mfma_f32_16x16x32_bf16(afr, b1, accT[mt * 2 + 1], 0, 0, 0);
    }
  }
  __syncthreads();  // tz dead; tgu overlay
#pragma unroll
  for (int mt = 0; mt < 4; mt++) {
#pragma unroll
    for (int ntl = 0; ntl < 2; ntl++) {
#pragma unroll
      for (int r = 0; r < 4; r++) {
        int nl = mt * 16 + quad * 4 + r;
        tgu[nl * 197 + 32 * w + ntl * 16 + l15] = accT[mt * 2 + ntl][r];
      }
    }
#pragma unroll
    for (int r = 0; r < 4; r++) {
      int nl = mt * 16 + quad * 4 + r;
      tgu[nl * 197 + 128 + 16 * w + l15] = accU[mt][r];
    }
  }
  __syncthreads();
  // epilogue: thread = node lane, col chunk c0
  int c0 = __builtin_amdgcn_readfirstlane(w * 16);
  int node = base + lane;
  int ngc = node < cBN ? node : cBN - 1;
  int bb = ngc / cN, nn = ngc - bb * cN;
  float hv[16];
  {
    const float4* hp = (const float4*)(h_nm + (size_t)ngc * 64 + c0);
#pragma unroll
    for (int q = 0; q < 4; q++) {
      float4 v = hp[q];
      hv[q * 4 + 0] = v.x; hv[q * 4 + 1] = v.y; hv[q * 4 + 2] = v.z; hv[q * 4 + 3] = v.w;
    }
  }
  float acc[16];
  float pm = 0.f;
#pragma unroll
  for (int c = 0; c < 16; c++) {
    float at = tgu[lane * 197 + c0 + c] + b_tau[c0 + c];
    float ag = tgu[lane * 197 + 64 + c0 + c] + b_g[c0 + c];
    float tau = 1.f + 9.f / (1.f + __expf(-at));
    float g = ftanh(ag);
    float v = hv[c] + 0.25f * (g - hv[c]) / tau;
    acc[c] = v;
    pm += v;
  }
  redm[w * 64 + lane] = pm;
  __syncthreads();
  float mu = (redm[lane] + redm[64 + lane] + redm[128 + lane] + redm[192 + lane]) * (1.f / 64.f);
  float pv = 0.f;
#pragma unroll
  for (int c = 0; c < 16; c++) {
    float d = acc[c] - mu;
    pv += d * d;
  }
  redv[w * 64 + lane] = pv;
  __syncthreads();
  float var = (redv[lane] + redv[64 + lane] + redv[128 + lane] + redv[192 + lane]) * (1.f / 64.f);
  float rstd = rsqrtf(var + 1e-5f);
#pragma unroll
  for (int c = 0; c < 16; c++) {
    acc[c] = (acc[c] - mu) * rstd * gamma[c0 + c] + beta[c0 + c] +
             tgu[lane * 197 + 128 + c0 + c] + b_enc[c0 + c];
  }
  if (node < cBN) {
    float4* hp = (float4*)(h_nm + (size_t)ngc * 64 + c0);
#pragma unroll
    for (int q = 0; q < 4; q++) {
      float4 v;
      v.x = acc[q * 4 + 0]; v.y = acc[q * 4 + 1]; v.z = acc[q * 4 + 2]; v.w = acc[q * 4 + 3];
      hp[q] = v;
    }
    unsigned* bp = (unsigned*)(h_bf + (size_t)ngc * 64 + c0);
#pragma unroll
    for (int q = 0; q < 8; q++) {
      unsigned lo = f2b(acc[q * 2 + 0]);
      unsigned hi = f2b(acc[q * 2 + 1]);
      bp[q] = (hi << 16) | lo;
    }
  }
  // decoder fastkan (RBF recurrence: 2 exps per col) + softplus
  float dc0 = cdec[0], dc7 = cdec[7];
  float inv_d = 7.f / (dc7 - dc0);
  float p0 = 0.f, p1 = 0.f, p2 = 0.f;
#pragma unroll
  for (int c = 0; c < 16; c++) {
    float d0 = (acc[c] - dc0) * inv_d;
    float ph = __expf(-d0 * d0);
    float r = __expf(2.f * d0 - 1.f);
    const float* Wd = W_dec + (c0 + c) * 24;
#pragma unroll
    for (int j = 0; j < 8; j++) {
      p0 += ph * Wd[j * 3];
      p1 += ph * Wd[j * 3 + 1];
      p2 += ph * Wd[j * 3 + 2];
      ph *= r;
      r *= cEXPM2;
    }
  }
  redp[(w * 3 + 0) * 64 + lane] = p0;
  redp[(w * 3 + 1) * 64 + lane] = p1;
  redp[(w * 3 + 2) * 64 + lane] = p2;
  __syncthreads();  // also: all tgu reads complete -> tail overlay safe
  if (w == 0 && node < cBN) {
    float v0 = redp[0 * 64 + lane] + redp[3 * 64 + lane] + redp[6 * 64 + lane] +
               redp[9 * 64 + lane] + b_dec[0];
    float v1 = redp[1 * 64 + lane] + redp[4 * 64 + lane] + redp[7 * 64 + lane] +
               redp[10 * 64 + lane] + b_dec[1];
    float v2 = redp[2 * 64 + lane] + redp[5 * 64 + lane] + redp[8 * 64 + lane] +
               redp[11 * 64 + lane] + b_dec[2];
    size_t ob = (((size_t)bb * cT + t) * cN + nn) * 3;
    out[ob] = fmaxf(v0, 0.f) + log1pf(__expf(-fabsf(v0)));
    out[ob + 1] = fmaxf(v1, 0.f) + log1pf(__expf(-fabsf(v1)));
    out[ob + 2] = fmaxf(v2, 0.f) + log1pf(__expf(-fabsf(v2)));
  }
  // ---- fused tail: next-step hop0 matvec (node-local: uses just-computed h) ----
#pragma unroll
  for (int c = 0; c < 16; c++) tzh[lane * 72 + c0 + c] = f2b(acc[c]);
  __syncthreads();
  f32x4 hacc[4];
#pragma unroll
  for (int mt = 0; mt < 4; mt++) hacc[mt] = (f32x4){0.f, 0.f, 0.f, 0.f};
#pragma unroll
  for (int ks = 0; ks < 2; ks++) {
    short8 bfr = *(const short8*)(Whop0 + (16 * w + l15) * 64 + ks * 32 + quad * 8);
#pragma unroll
    for (int mt = 0; mt < 4; mt++) {
      short8 afr = *(const short8*)(tzh + (mt * 16 + l15) * 72 + ks * 32 + quad * 8);
      hacc[mt] = __builtin_amdgcn_mfma_f32_16x16x32_bf16(afr, bfr, hacc[mt], 0, 0, 0);
    }
  }
  int colh = 16 * w + l15;
#pragma unroll
  for (int mt = 0; mt < 4; mt++) {
#pragma unroll
    for (int r = 0; r < 4; r++) {
      thw2[(mt * 16 + quad * 4 + r) * 72 + colh] = f2b(hacc[mt][r]);
    }
  }
  __syncthreads();
  {
    float r1 = 0.f, r2 = 0.f;
#pragma unroll
    for (int c = 0; c < 16; c++) {
      float v = b2f(thw2[lane * 72 + 16 * w + c]);
      r1 += v * avs0[16 * w + c];
      r2 += v * avd0[16 * w + c];
    }
    redm[w * 64 + lane] = r1;
    redv[w * 64 + lane] = r2;
  }
  __syncthreads();
  if (w == 0 && node < cBN) {
    ssrc[node] = redm[lane] + redm[64 + lane] + redm[128 + lane] + redm[192 + lane];
    sdst[node] = redv[lane] + redv[64 + lane] + redv[128 + lane] + redv[192 + lane];
  }
  {
    int tn = tid >> 2, cs = (tid & 3) * 16;
    int gn = base + tn;
    if (gn < cBN) {
      short8* dst = (short8*)(hw_bf + (size_t)gn * 64 + cs);
      dst[0] = *(const short8*)(thw2 + tn * 72 + cs);
      dst[1] = *(const short8*)(thw2 + tn * 72 + cs + 8);
    }
  }
}

extern "C" void kernel_launch(void* const* d_in, const int* in_sizes, int n_in, void* d_out,
                              int out_size, void* d_ws, size_t ws_size, hipStream_t stream) {
  fp x = (fp)d_in[0];
  fp edge_attr = (fp)d_in[1];
  fp c_enc = (fp)d_in[2];
  fp W_enc = (fp)d_in[3];
  fp b_enc = (fp)d_in[4];
  fp W_hop = (fp)d_in[5];
  fp a_src = (fp)d_in[6];
  fp a_dst = (fp)d_in[7];
  fp w_lt1 = (fp)d_in[8];
  fp b_lt1 = (fp)d_in[9];
  fp w_lt2 = (fp)d_in[10];
  fp b_lt2 = (fp)d_in[11];
  fp W_lt = (fp)d_in[12];
  fp W_tau = (fp)d_in[13];
  fp b_tau = (fp)d_in[14];
  fp W_g = (fp)d_in[15];
  fp b_g = (fp)d_in[16];
  fp gamma = (fp)d_in[17];
  fp beta = (fp)d_in[18];
  fp c_dec = (fp)d_in[19];
  fp W_dec = (fp)d_in[20];
  fp b_dec = (fp)d_in[21];
  fp h0 = (fp)d_in[22];
  const int* eidx = (const int*)d_in[23];
  const int* esrc_in = eidx;
  const int* edst_in = eidx + cE;

  float* fws = (float*)d_ws;
  float* h_nm = fws;   fws += cBNH;
  float* khsum = fws;  fws += cBNH;
  float* ssrc = fws;   fws += cBN;
  float* sdst = fws;   fws += cBN;
  float* ssrc2 = fws;  fws += cBN;
  float* sdst2 = fws;  fws += cBN;
  float* gcsr = fws;   fws += cE;
  u16* h_bf = (u16*)fws;    fws += cBNH / 2;
  u16* hw_bf = (u16*)fws;   fws += cBNH / 2;
  u16* hw_bf2 = (u16*)fws;  fws += cBNH / 2;
  u16* agg_bf = (u16*)fws;  fws += cBNH / 2;
  u16* Wtg = (u16*)fws;   fws += (128 * 160) / 2;
  u16* Wenc = (u16*)fws;  fws += (64 * 128) / 2;
  u16* Wlt = (u16*)fws;   fws += (64 * 64) / 2;
  u16* Whop = (u16*)fws;  fws += (3 * 64 * 64) / 2;
  int* iws = (int*)fws;
  int* esrc = iws;    iws += cE;
  int* row_ptr = iws; iws += cN + 1;
  int* cursor = iws;  iws += cN;
  int* counts = iws;  iws += cN;
  int* perm = iws;    iws += cN;

  k_setup<<<(cBNH + 255) / 256, 256, 0, stream>>>(counts, h_nm, h_bf, h0, W_tau, W_g, W_enc,
                                                  W_lt, W_hop, Wtg, Wenc, Wlt, Whop);
  k_count<<<(cE + 255) / 256, 256, 0, stream>>>(edst_in, counts);
  k_scan<<<1, 1024, 0, stream>>>(counts, row_ptr, cursor);
  k_dsort<<<1, 1024, 0, stream>>>(counts, perm);
  k_scatter<<<(cE + 255) / 256, 256, 0, stream>>>(esrc_in, edst_in, edge_attr, w_lt1, b_lt1,
                                                  w_lt2, b_lt2, cursor, esrc, gcsr);
  // initial hop0 matvec for t=0 (later steps get it fused into k_mega's tail)
  k_hop_mat_m<<<NBLK, 256, 0, stream>>>(h_bf, Whop, a_src, a_dst, hw_bf, ssrc, sdst);

  for (int t = 0; t < cT; t++) {
    // hop0 (+larval): read set0, fused mat writes set1
    k_hop_agg<0><<<ABLK, 256, 0, stream>>>(hw_bf, ssrc, sdst, row_ptr, esrc, gcsr, h_bf,
                                           khsum, agg_bf, perm, Whop + 4096, a_src + cH,
                                           a_dst + cH, hw_bf2, ssrc2, sdst2);
    // hop1: read set1, fused mat writes set0
    k_hop_agg<1><<<ABLK, 256, 0, stream>>>(hw_bf2, ssrc2, sdst2, row_ptr, esrc, gcsr, h_bf,
                                           khsum, agg_bf, perm, Whop + 2 * 4096,
                                           a_src + 2 * cH, a_dst + 2 * cH, hw_bf, ssrc, sdst);
    // hop2: read set0, no fused mat
    k_hop_agg<2><<<ABLK, 256, 0, stream>>>(hw_bf, ssrc, sdst, row_ptr, esrc, gcsr, h_bf,
                                           khsum, agg_bf, perm, nullptr, nullptr, nullptr,
                                           nullptr, nullptr, nullptr);
    k_mega<<<NBLK, 256, 0, stream>>>(x, t, h_nm, h_bf, khsum, agg_bf, row_ptr, Wtg, Wenc, Wlt,
                                     Whop, a_src, a_dst, hw_bf, ssrc, sdst, b_tau, b_g, b_enc,
                                     gamma, beta, c_enc, c_dec, W_dec, b_dec, (float*)d_out);
  }
}